// Round 3
// baseline (599.086 us; speedup 1.0000x reference)
//
#include <hip/hip_runtime.h>
#include <math.h>

#define NBATCH 8
#define HWDIM  56
#define NWIN   7
#define P2     49
#define HEADS  8
#define TOPK   4
#define SCALE  0.0625f
#define NPIX   (NBATCH*HWDIM*HWDIM)   // 25088

typedef __attribute__((ext_vector_type(8))) short bf16x8;
typedef __attribute__((ext_vector_type(4))) float f32x4;

__device__ __forceinline__ unsigned short f2bf(float f) {
  unsigned u = __float_as_uint(f);
  u += 0x7FFF + ((u >> 16) & 1);
  return (unsigned short)(u >> 16);
}
__device__ __forceinline__ float bf2f(unsigned short h) {
  return __uint_as_float(((unsigned)h) << 16);
}

// ---------------------------------------------------------------------------
// x (fp32) -> x_bf (bf16), 8 elems/thread
// ---------------------------------------------------------------------------
__global__ __launch_bounds__(256) void convert_x(
    const float* __restrict__ xin, unsigned short* __restrict__ xb)
{
  const int i = (blockIdx.x * 256 + threadIdx.x) * 8;
  float4 a = *(const float4*)&xin[i];
  float4 b = *(const float4*)&xin[i + 4];
  ushort4 o0 = { f2bf(a.x), f2bf(a.y), f2bf(a.z), f2bf(a.w) };
  ushort4 o1 = { f2bf(b.x), f2bf(b.y), f2bf(b.z), f2bf(b.w) };
  *(ushort4*)&xb[i] = o0;
  *(ushort4*)&xb[i + 4] = o1;
}

// ---------------------------------------------------------------------------
// Weight prep: Wt_qkv[n][k] = W_qkv[k][n] (*SCALE for n<256), bf16
//              Wt_o[n][k]   = W_o[k][n], bf16;  b_s = b_qkv (*SCALE for <256)
// ---------------------------------------------------------------------------
__global__ __launch_bounds__(256) void prep_w(
    const float* __restrict__ W_qkv, const float* __restrict__ b_qkv,
    const float* __restrict__ W_o,
    unsigned short* __restrict__ Wt_qkv, unsigned short* __restrict__ Wt_o,
    float* __restrict__ b_s)
{
  const int idx = blockIdx.x * 256 + threadIdx.x;
  if (idx < 768 * 256) {
    const int nn = idx >> 8, cc = idx & 255;
    float v = W_qkv[cc * 768 + nn];
    if (nn < 256) v *= SCALE;
    Wt_qkv[idx] = f2bf(v);
  } else if (idx < 768 * 256 + 256 * 256) {
    const int j = idx - 768 * 256;
    const int nn = j >> 8, cc = j & 255;
    Wt_o[j] = f2bf(W_o[cc * 256 + nn]);
  } else if (idx < 768 * 256 + 256 * 256 + 768) {
    const int j = idx - (768 * 256 + 256 * 256);
    b_s[j] = b_qkv[j] * (j < 256 ? SCALE : 1.f);
  }
}

// ---------------------------------------------------------------------------
// Window means of x (fp32, exact routing path). grid = N*P2
// ---------------------------------------------------------------------------
__global__ __launch_bounds__(256) void x_win_kernel(
    const float* __restrict__ x, float* __restrict__ xw)
{
  const int bidx = blockIdx.x;
  const int n = bidx / P2, p = bidx - n * P2;
  const int c = threadIdx.x;
  const int y0 = (p / NWIN) * 8, x0 = (p % NWIN) * 8;
  float s = 0.f;
  for (int tpx = 0; tpx < 64; ++tpx) {
    const int yy = y0 + (tpx >> 3), xx = x0 + (tpx & 7);
    s += x[((size_t)((n * HWDIM + yy) * HWDIM + xx)) * 256 + c];
  }
  xw[(size_t)bidx * 256 + c] = s * (1.f / 64.f);
}

// ---------------------------------------------------------------------------
// q_win/k_win = x_win @ W_qkv[:, :512] + b (fp32 exact). grid = N*P2
// ---------------------------------------------------------------------------
__global__ __launch_bounds__(256) void win_gemm(
    const float* __restrict__ xw, const float* __restrict__ W_qkv,
    const float* __restrict__ b_qkv,
    float* __restrict__ q_win, float* __restrict__ k_win)
{
  __shared__ float xs[256];
  const int bidx = blockIdx.x;
  const int t = threadIdx.x;
  xs[t] = xw[(size_t)bidx * 256 + t];
  __syncthreads();
  float aq = 0.f, ak = 0.f;
  for (int cc = 0; cc < 256; ++cc) {
    const float xv = xs[cc];
    aq = fmaf(xv, W_qkv[cc * 768 + t], aq);
    ak = fmaf(xv, W_qkv[cc * 768 + 256 + t], ak);
  }
  q_win[(size_t)bidx * 256 + t] = aq + b_qkv[t];
  k_win[(size_t)bidx * 256 + t] = ak + b_qkv[256 + t];
}

// ---------------------------------------------------------------------------
// Routing: 49x49 logits per image, top-4 per row (fp32). grid = N
// ---------------------------------------------------------------------------
__global__ __launch_bounds__(256) void routing_topk(
    const float* __restrict__ q_win, const float* __restrict__ k_win,
    int* __restrict__ r_idx)
{
  __shared__ float logit[P2][P2 + 1];
  const int n = blockIdx.x, tid = threadIdx.x;
  const float* qb = q_win + (size_t)n * P2 * 256;
  const float* kb = k_win + (size_t)n * P2 * 256;
  for (int idx = tid; idx < P2 * P2; idx += 256) {
    const int p = idx / P2, qq = idx - p * P2;
    float acc = 0.f;
    for (int c = 0; c < 256; ++c)
      acc = fmaf(qb[p * 256 + c], kb[qq * 256 + c], acc);
    logit[p][qq] = acc * SCALE;
  }
  __syncthreads();
  if (tid < P2) {
    float bv0 = -3e38f, bv1 = -3e38f, bv2 = -3e38f, bv3 = -3e38f;
    int bi0 = 0, bi1 = 0, bi2 = 0, bi3 = 0;
    for (int qq = 0; qq < P2; ++qq) {
      const float v = logit[tid][qq];
      if (v > bv0) { bv3=bv2; bi3=bi2; bv2=bv1; bi2=bi1; bv1=bv0; bi1=bi0; bv0=v; bi0=qq; }
      else if (v > bv1) { bv3=bv2; bi3=bi2; bv2=bv1; bi2=bi1; bv1=v; bi1=qq; }
      else if (v > bv2) { bv3=bv2; bi3=bi2; bv2=v; bi2=qq; }
      else if (v > bv3) { bv3=v; bi3=qq; }
    }
    int* rp = r_idx + (size_t)(n * P2 + tid) * TOPK;
    rp[0] = bi0; rp[1] = bi1; rp[2] = bi2; rp[3] = bi3;
  }
}

// ---------------------------------------------------------------------------
// bf16 MFMA GEMM: C[M][*] = A[M][256] @ Bt[N][256]^T + bias
// 128x128 tile, BK=64, 4 waves, reg-staged LDS, repacked coalesced epilogue.
// MODE 0: bf16 out split into C0/C1/C2 by bn>>1 (QKV). MODE 1: fp32 out Cf.
// ---------------------------------------------------------------------------
template<int MODE>
__global__ __launch_bounds__(256) void gemm_mfma(
    const unsigned short* __restrict__ A,
    const unsigned short* __restrict__ Bt,
    const float* __restrict__ bias,
    unsigned short* __restrict__ C0, unsigned short* __restrict__ C1,
    unsigned short* __restrict__ C2, float* __restrict__ Cf)
{
  __shared__ char smem[32768];
  unsigned short* Asm = (unsigned short*)smem;            // [128][64] bf16
  unsigned short* Bsm = (unsigned short*)(smem + 16384);  // [128][64] bf16
  float* Cs = (float*)smem;                               // [64][128] f32 (reuse)

  const int t = threadIdx.x;
  const int w = t >> 6, l = t & 63;
  const int wr = w >> 1, wc = w & 1;
  const int lr = l & 15, lg = l >> 4;
  const int bm = blockIdx.x, bn = blockIdx.y;
  const int row0 = bm * 128, col0 = bn * 128;

  const f32x4 fzero = {0.f, 0.f, 0.f, 0.f};
  f32x4 acc[4][4];
  #pragma unroll
  for (int m = 0; m < 4; ++m)
    #pragma unroll
    for (int n = 0; n < 4; ++n) acc[m][n] = fzero;

  const int srow = t >> 3, skoff = (t & 7) * 8;
  bf16x8 ra[4], rb[4];
  #pragma unroll
  for (int i = 0; i < 4; ++i) {
    ra[i] = *(const bf16x8*)&A [(size_t)(row0 + i*32 + srow) * 256 + skoff];
    rb[i] = *(const bf16x8*)&Bt[(size_t)(col0 + i*32 + srow) * 256 + skoff];
  }

  for (int step = 0; step < 4; ++step) {
    __syncthreads();
    #pragma unroll
    for (int i = 0; i < 4; ++i) {
      *(bf16x8*)&Asm[(i*32 + srow) * 64 + skoff] = ra[i];
      *(bf16x8*)&Bsm[(i*32 + srow) * 64 + skoff] = rb[i];
    }
    __syncthreads();
    if (step < 3) {
      const int k1 = (step + 1) * 64;
      #pragma unroll
      for (int i = 0; i < 4; ++i) {
        ra[i] = *(const bf16x8*)&A [(size_t)(row0 + i*32 + srow) * 256 + k1 + skoff];
        rb[i] = *(const bf16x8*)&Bt[(size_t)(col0 + i*32 + srow) * 256 + k1 + skoff];
      }
    }
    #pragma unroll
    for (int kk = 0; kk < 2; ++kk) {
      bf16x8 af[4], bb[4];
      #pragma unroll
      for (int m = 0; m < 4; ++m)
        af[m] = *(const bf16x8*)&Asm[(wr*64 + m*16 + lr) * 64 + kk*32 + lg*8];
      #pragma unroll
      for (int n = 0; n < 4; ++n)
        bb[n] = *(const bf16x8*)&Bsm[(wc*64 + n*16 + lr) * 64 + kk*32 + lg*8];
      #pragma unroll
      for (int m = 0; m < 4; ++m)
        #pragma unroll
        for (int n = 0; n < 4; ++n)
          acc[m][n] = __builtin_amdgcn_mfma_f32_16x16x32_bf16(af[m], bb[n], acc[m][n], 0, 0, 0);
    }
  }

  float bcol[4];
  #pragma unroll
  for (int n = 0; n < 4; ++n) bcol[n] = bias[col0 + wc*64 + n*16 + lr];

  #pragma unroll
  for (int hf = 0; hf < 2; ++hf) {
    __syncthreads();
    if (wr == hf) {
      #pragma unroll
      for (int m = 0; m < 4; ++m)
        #pragma unroll
        for (int n = 0; n < 4; ++n)
          #pragma unroll
          for (int r = 0; r < 4; ++r) {
            const int lrow = m*16 + lg*4 + r;           // 0..63
            const int col  = wc*64 + n*16 + lr;         // 0..127
            const int csw  = col ^ ((lrow & 7) << 2);
            Cs[lrow * 128 + csw] = acc[m][n][r] + bcol[n];
          }
    }
    __syncthreads();
    #pragma unroll
    for (int it = 0; it < 8; ++it) {
      const int d = (it * 256 + t) * 4;
      const int lrow = d >> 7;
      const int colL = (d & 127) ^ ((lrow & 7) << 2);
      f32x4 v = *(const f32x4*)&Cs[d];
      const size_t grow = (size_t)(row0 + hf*64 + lrow);
      if (MODE == 0) {
        unsigned short* Cp = (bn < 2) ? C0 : (bn < 4) ? C1 : C2;
        const int lc = (bn & 1) * 128 + colL;
        ushort4 o = { f2bf(v[0]), f2bf(v[1]), f2bf(v[2]), f2bf(v[3]) };
        *(ushort4*)&Cp[grow * 256 + lc] = o;
      } else {
        float4 o = { v[0], v[1], v[2], v[3] };
        *(float4*)&Cf[grow * 256 + (size_t)(bn * 128) + colL] = o;
      }
    }
  }
}

// ---------------------------------------------------------------------------
// MFMA gathered attention. grid = N*P2*HEADS (b&7 = head), 256 threads / 4 waves.
// QK^T (16 mfma/wave) -> wave-parallel softmax -> P(bf16,swizzled LDS)
// -> PV (16 mfma/wave) -> LDS repack -> coalesced bf16 store.
// ---------------------------------------------------------------------------
#define KPAD 40      // K/Q row stride (elems) = 80B
#define PSTR 264     // P/VT row stride (elems) = 528B

__global__ __launch_bounds__(256) void attn_mfma(
    const unsigned short* __restrict__ q_bf,
    const unsigned short* __restrict__ k_bf,
    const unsigned short* __restrict__ v_bf,
    const int* __restrict__ r_idx,
    unsigned short* __restrict__ o_bf)
{
  __shared__ char smem[76288];
  unsigned short* Ksm = (unsigned short*)smem;              // [256][KPAD]
  unsigned short* Vsm = (unsigned short*)(smem + 20480);    // [32][PSTR]  (V^T)
  unsigned short* Qsm = (unsigned short*)(smem + 37376);    // [64][KPAD]
  unsigned short* Psm = (unsigned short*)(smem + 42496);    // [64][PSTR]
  float* Osm = (float*)smem;                                // [64][36] f32 (over Ksm)

  const int b = blockIdx.x;
  const int h = b & 7;
  const int np = b >> 3;
  const int n = np / P2, p = np - n * P2;
  const int t = threadIdx.x;
  const int w = t >> 6, l = t & 63;
  const int lr = l & 15, lg = l >> 4;

  // ---- stage K (row-major, padded) and V^T ----
  {
    const int wv = r_idx[np * 4 + (t >> 6)];
    const int pix = t & 63;
    const int ky = (wv / NWIN) * 8 + (pix >> 3);
    const int kx = (wv % NWIN) * 8 + (pix & 7);
    const size_t goff = ((size_t)((n * HWDIM + ky) * HWDIM + kx)) * 256 + h * 32;
    #pragma unroll
    for (int j = 0; j < 4; ++j) {
      bf16x8 kv = *(const bf16x8*)&k_bf[goff + j * 8];
      *(bf16x8*)&Ksm[t * KPAD + j * 8] = kv;
      bf16x8 vv = *(const bf16x8*)&v_bf[goff + j * 8];
      #pragma unroll
      for (int e = 0; e < 8; ++e)
        Vsm[(j * 8 + e) * PSTR + t] = (unsigned short)vv[e];
    }
  }
  // ---- stage Q ----
  {
    const int qr = t >> 2, jq = t & 3;
    const int qy = (p / NWIN) * 8 + (qr >> 3);
    const int qx = (p % NWIN) * 8 + (qr & 7);
    *(bf16x8*)&Qsm[qr * KPAD + jq * 8] =
        *(const bf16x8*)&q_bf[((size_t)((n * HWDIM + qy) * HWDIM + qx)) * 256 + h * 32 + jq * 8];
  }
  __syncthreads();

  // ---- QK^T : wave w owns q rows [w*16, w*16+16) ----
  f32x4 sf[16];
  {
    const f32x4 fzero = {0.f, 0.f, 0.f, 0.f};
    bf16x8 aq = *(const bf16x8*)&Qsm[(w * 16 + lr) * KPAD + lg * 8];
    #pragma unroll
    for (int f = 0; f < 16; ++f) {
      bf16x8 bk = *(const bf16x8*)&Ksm[(f * 16 + lr) * KPAD + lg * 8];
      sf[f] = __builtin_amdgcn_mfma_f32_16x16x32_bf16(aq, bk, fzero, 0, 0, 0);
    }
  }

  // ---- softmax (rows q = w*16 + lg*4 + r; cols split over 16 lr lanes) ----
  float inv[4];
  #pragma unroll
  for (int r = 0; r < 4; ++r) {
    float mx = sf[0][r];
    #pragma unroll
    for (int f = 1; f < 16; ++f) mx = fmaxf(mx, sf[f][r]);
    mx = fmaxf(mx, __shfl_xor(mx, 1));
    mx = fmaxf(mx, __shfl_xor(mx, 2));
    mx = fmaxf(mx, __shfl_xor(mx, 4));
    mx = fmaxf(mx, __shfl_xor(mx, 8));
    float sum = 0.f;
    #pragma unroll
    for (int f = 0; f < 16; ++f) { float e = __expf(sf[f][r] - mx); sf[f][r] = e; sum += e; }
    sum += __shfl_xor(sum, 1);
    sum += __shfl_xor(sum, 2);
    sum += __shfl_xor(sum, 4);
    sum += __shfl_xor(sum, 8);
    inv[r] = 1.f / sum;
  }
  // write normalized P as bf16 with key-block XOR swizzle
  #pragma unroll
  for (int f = 0; f < 16; ++f)
    #pragma unroll
    for (int r = 0; r < 4; ++r) {
      const int q = w * 16 + lg * 4 + r;
      const int key = f * 16 + lr;
      const int blk = (key >> 3) ^ (q & 7);
      Psm[q * PSTR + blk * 8 + (key & 7)] = f2bf(sf[f][r] * inv[r]);
    }
  __syncthreads();

  // ---- PV : out[q][d] = P[q][:] . V[:, d] ----
  f32x4 oacc[2];
  oacc[0] = (f32x4){0.f, 0.f, 0.f, 0.f};
  oacc[1] = (f32x4){0.f, 0.f, 0.f, 0.f};
  #pragma unroll
  for (int ks = 0; ks < 8; ++ks) {
    const int ablk = (ks * 4 + lg) ^ (lr & 7);
    bf16x8 ap = *(const bf16x8*)&Psm[(w * 16 + lr) * PSTR + ablk * 8];
    #pragma unroll
    for (int nn = 0; nn < 2; ++nn) {
      bf16x8 bv = *(const bf16x8*)&Vsm[(nn * 16 + lr) * PSTR + ks * 32 + lg * 8];
      oacc[nn] = __builtin_amdgcn_mfma_f32_16x16x32_bf16(ap, bv, oacc[nn], 0, 0, 0);
    }
  }

  // ---- repack through LDS, coalesced bf16 store ----
  #pragma unroll
  for (int nn = 0; nn < 2; ++nn)
    #pragma unroll
    for (int r = 0; r < 4; ++r)
      Osm[(w * 16 + lg * 4 + r) * 36 + nn * 16 + lr] = oacc[nn][r];
  __syncthreads();
  {
    const int q = t >> 2, dq = (t & 3) * 8;
    const int qy = (p / NWIN) * 8 + (q >> 3);
    const int qx = (p % NWIN) * 8 + (q & 7);
    float vo[8];
    #pragma unroll
    for (int e = 0; e < 8; ++e) vo[e] = Osm[q * 36 + dq + e];
    ushort4 o0 = { f2bf(vo[0]), f2bf(vo[1]), f2bf(vo[2]), f2bf(vo[3]) };
    ushort4 o1 = { f2bf(vo[4]), f2bf(vo[5]), f2bf(vo[6]), f2bf(vo[7]) };
    unsigned short* op = &o_bf[((size_t)((n * HWDIM + qy) * HWDIM + qx)) * 256 + h * 32 + dq];
    *(ushort4*)op = o0;
    *(ushort4*)&op[4] = o1;
  }
}

// ---------------------------------------------------------------------------
// LEPE: 5x5 depthwise conv over v (bf16), added into attn output (bf16).
// grid = N*56 (n, x-column), 256 threads = channels; sweep y.
// ---------------------------------------------------------------------------
__global__ __launch_bounds__(256) void lepe_add(
    const unsigned short* __restrict__ v_bf,
    const float* __restrict__ wconv, const float* __restrict__ bias,
    unsigned short* __restrict__ o_bf)
{
  const int blk = blockIdx.x;
  const int n = blk / HWDIM, x = blk % HWDIM;
  const int c = threadIdx.x;
  float wk[25];
  #pragma unroll
  for (int i = 0; i < 25; ++i) wk[i] = wconv[c * 25 + i];
  const float bc = bias[c];
  for (int y = 0; y < HWDIM; ++y) {
    float acc = bc;
    #pragma unroll
    for (int ky = 0; ky < 5; ++ky) {
      const int sy = y + ky - 2;
      if (sy < 0 || sy >= HWDIM) continue;
      #pragma unroll
      for (int kx = 0; kx < 5; ++kx) {
        const int sx = x + kx - 2;
        if (sx < 0 || sx >= HWDIM) continue;
        acc = fmaf(wk[ky * 5 + kx],
                   bf2f(v_bf[((size_t)((n * HWDIM + sy) * HWDIM + sx)) * 256 + c]), acc);
      }
    }
    const size_t oo = ((size_t)((n * HWDIM + y) * HWDIM + x)) * 256 + c;
    o_bf[oo] = f2bf(bf2f(o_bf[oo]) + acc);
  }
}

// ---------------------------------------------------------------------------
extern "C" void kernel_launch(void* const* d_in, const int* in_sizes, int n_in,
                              void* d_out, int out_size, void* d_ws, size_t ws_size,
                              hipStream_t stream)
{
  const float* x      = (const float*)d_in[0];
  const float* W_qkv  = (const float*)d_in[1];
  const float* b_qkv  = (const float*)d_in[2];
  const float* lepe_w = (const float*)d_in[3];
  const float* lepe_b = (const float*)d_in[4];
  const float* W_o    = (const float*)d_in[5];
  const float* b_o    = (const float*)d_in[6];
  float* out = (float*)d_out;

  char* ws = (char*)d_ws;
  const size_t IMG = (size_t)NPIX * 256;          // elems per image buffer
  unsigned short* x_bf    = (unsigned short*)(ws);
  unsigned short* q_bf    = (unsigned short*)(ws + 2*IMG);
  unsigned short* k_bf    = (unsigned short*)(ws + 4*IMG);
  unsigned short* v_bf    = (unsigned short*)(ws + 6*IMG);
  unsigned short* attn_bf = (unsigned short*)(ws + 8*IMG);
  unsigned short* Wt_qkv  = (unsigned short*)(ws + 10*IMG);
  unsigned short* Wt_o    = (unsigned short*)(ws + 10*IMG + 393216);
  float*          b_s     = (float*)         (ws + 10*IMG + 393216 + 131072);
  float*          x_win   = (float*)         (ws + 10*IMG + 393216 + 131072 + 4096);
  float*          q_win   = x_win + (size_t)NBATCH * P2 * 256;
  float*          k_win   = q_win + (size_t)NBATCH * P2 * 256;
  int*            ridx    = (int*)(k_win + (size_t)NBATCH * P2 * 256);

  convert_x<<<3136, 256, 0, stream>>>(x, x_bf);
  prep_w<<<1027, 256, 0, stream>>>(W_qkv, b_qkv, W_o, Wt_qkv, Wt_o, b_s);
  x_win_kernel<<<NBATCH * P2, 256, 0, stream>>>(x, x_win);
  win_gemm<<<NBATCH * P2, 256, 0, stream>>>(x_win, W_qkv, b_qkv, q_win, k_win);
  routing_topk<<<NBATCH, 256, 0, stream>>>(q_win, k_win, ridx);
  gemm_mfma<0><<<dim3(196, 6), 256, 0, stream>>>(x_bf, Wt_qkv, b_s,
                                                 q_bf, k_bf, v_bf, nullptr);
  attn_mfma<<<NBATCH * P2 * HEADS, 256, 0, stream>>>(q_bf, k_bf, v_bf, ridx, attn_bf);
  lepe_add<<<NBATCH * HWDIM, 256, 0, stream>>>(v_bf, lepe_w, lepe_b, attn_bf);
  gemm_mfma<1><<<dim3(196, 2), 256, 0, stream>>>(attn_bf, Wt_o, b_o,
                                                 nullptr, nullptr, nullptr, out);
}

// Round 4
// 238.553 us; speedup vs baseline: 2.5113x; 2.5113x over previous
//
#include <hip/hip_runtime.h>
#include <math.h>

#define NBATCH 8
#define HWDIM  56
#define NWIN   7
#define P2     49
#define HEADS  8
#define TOPK   4
#define SCALE  0.0625f
#define NPIX   (NBATCH*HWDIM*HWDIM)   // 25088

typedef __attribute__((ext_vector_type(8))) short bf16x8;
typedef __attribute__((ext_vector_type(4))) float f32x4;

__device__ __forceinline__ unsigned short f2bf(float f) {
  unsigned u = __float_as_uint(f);
  u += 0x7FFF + ((u >> 16) & 1);
  return (unsigned short)(u >> 16);
}
__device__ __forceinline__ float bf2f(unsigned short h) {
  return __uint_as_float(((unsigned)h) << 16);
}

// ---------------------------------------------------------------------------
// x (fp32) -> x_bf (bf16), 8 elems/thread
// ---------------------------------------------------------------------------
__global__ __launch_bounds__(256) void convert_x(
    const float* __restrict__ xin, unsigned short* __restrict__ xb)
{
  const int i = (blockIdx.x * 256 + threadIdx.x) * 8;
  float4 a = *(const float4*)&xin[i];
  float4 b = *(const float4*)&xin[i + 4];
  ushort4 o0 = { f2bf(a.x), f2bf(a.y), f2bf(a.z), f2bf(a.w) };
  ushort4 o1 = { f2bf(b.x), f2bf(b.y), f2bf(b.z), f2bf(b.w) };
  *(ushort4*)&xb[i] = o0;
  *(ushort4*)&xb[i + 4] = o1;
}

// ---------------------------------------------------------------------------
// Weight prep: Wt_qkv[n][k] = W_qkv[k][n] (*SCALE for n<256), bf16
//              Wt_o[n][k]   = W_o[k][n], bf16;  b_s = b_qkv (*SCALE for <256)
//              Wc[tap][c]   = lepe_w[c][tap]  (fp32)
// ---------------------------------------------------------------------------
__global__ __launch_bounds__(256) void prep_w(
    const float* __restrict__ W_qkv, const float* __restrict__ b_qkv,
    const float* __restrict__ W_o, const float* __restrict__ lepe_w,
    unsigned short* __restrict__ Wt_qkv, unsigned short* __restrict__ Wt_o,
    float* __restrict__ b_s, float* __restrict__ Wc)
{
  const int idx = blockIdx.x * 256 + threadIdx.x;
  if (idx < 768 * 256) {
    const int nn = idx >> 8, cc = idx & 255;
    float v = W_qkv[cc * 768 + nn];
    if (nn < 256) v *= SCALE;
    Wt_qkv[idx] = f2bf(v);
  } else if (idx < 768 * 256 + 256 * 256) {
    const int j = idx - 768 * 256;
    const int nn = j >> 8, cc = j & 255;
    Wt_o[j] = f2bf(W_o[cc * 256 + nn]);
  } else if (idx < 768 * 256 + 256 * 256 + 768) {
    const int j = idx - (768 * 256 + 256 * 256);
    b_s[j] = b_qkv[j] * (j < 256 ? SCALE : 1.f);
  } else if (idx < 768 * 256 + 256 * 256 + 768 + 25 * 256) {
    const int j = idx - (768 * 256 + 256 * 256 + 768);
    const int tap = j >> 8, cc = j & 255;
    Wc[j] = lepe_w[cc * 25 + tap];
  }
}

// ---------------------------------------------------------------------------
// Window means of x (fp32, exact routing path). grid = N*P2, float4 loads.
// ---------------------------------------------------------------------------
__global__ __launch_bounds__(256) void x_win_kernel(
    const float* __restrict__ x, float* __restrict__ xw)
{
  __shared__ float4 red[256];
  const int bidx = blockIdx.x;
  const int n = bidx / P2, p = bidx - n * P2;
  const int y0 = (p / NWIN) * 8, x0 = (p % NWIN) * 8;
  const int t = threadIdx.x;
  const int c4 = t & 63, pg = t >> 6;
  float4 s = {0.f, 0.f, 0.f, 0.f};
  #pragma unroll
  for (int k = 0; k < 16; ++k) {
    const int pix = pg * 16 + k;
    const int yy = y0 + (pix >> 3), xx = x0 + (pix & 7);
    float4 v = *(const float4*)&x[((size_t)((n * HWDIM + yy) * HWDIM + xx)) * 256 + c4 * 4];
    s.x += v.x; s.y += v.y; s.z += v.z; s.w += v.w;
  }
  red[t] = s;
  __syncthreads();
  if (pg == 0) {
    float4 a = red[c4], b = red[64 + c4], c = red[128 + c4], d = red[192 + c4];
    float4 o = { (a.x + b.x + c.x + d.x) * (1.f/64.f),
                 (a.y + b.y + c.y + d.y) * (1.f/64.f),
                 (a.z + b.z + c.z + d.z) * (1.f/64.f),
                 (a.w + b.w + c.w + d.w) * (1.f/64.f) };
    *(float4*)&xw[(size_t)bidx * 256 + c4 * 4] = o;
  }
}

// ---------------------------------------------------------------------------
// q_win/k_win = x_win @ W_qkv[:, :512] + b (fp32 exact). grid = N*P2
// ---------------------------------------------------------------------------
__global__ __launch_bounds__(256) void win_gemm(
    const float* __restrict__ xw, const float* __restrict__ W_qkv,
    const float* __restrict__ b_qkv,
    float* __restrict__ q_win, float* __restrict__ k_win)
{
  __shared__ float xs[256];
  const int bidx = blockIdx.x;
  const int t = threadIdx.x;
  xs[t] = xw[(size_t)bidx * 256 + t];
  __syncthreads();
  float aq = 0.f, ak = 0.f;
  for (int cc = 0; cc < 256; ++cc) {
    const float xv = xs[cc];
    aq = fmaf(xv, W_qkv[cc * 768 + t], aq);
    ak = fmaf(xv, W_qkv[cc * 768 + 256 + t], ak);
  }
  q_win[(size_t)bidx * 256 + t] = aq + b_qkv[t];
  k_win[(size_t)bidx * 256 + t] = ak + b_qkv[256 + t];
}

// ---------------------------------------------------------------------------
// Routing: grid = N*P2 blocks; 4 lanes x 64ch partials per logit;
// top-4 scan of 49 by lane 0. SCALE>0 is order-preserving -> omitted.
// ---------------------------------------------------------------------------
__global__ __launch_bounds__(256) void routing_topk(
    const float* __restrict__ q_win, const float* __restrict__ k_win,
    int* __restrict__ r_idx)
{
  __shared__ float qs[256];
  __shared__ float logit[64];
  const int bidx = blockIdx.x;
  const int n = bidx / P2;
  const int t = threadIdx.x;
  qs[t] = q_win[(size_t)bidx * 256 + t];
  __syncthreads();
  const int qq = t >> 2, qt = t & 3;
  if (qq < P2) {
    const float* kb = k_win + ((size_t)(n * P2 + qq)) * 256 + qt * 64;
    float a = 0.f;
    #pragma unroll 8
    for (int i = 0; i < 64; ++i) a = fmaf(qs[qt * 64 + i], kb[i], a);
    a += __shfl_xor(a, 1);
    a += __shfl_xor(a, 2);
    if (qt == 0) logit[qq] = a;
  }
  __syncthreads();
  if (t == 0) {
    float bv0 = -3e38f, bv1 = -3e38f, bv2 = -3e38f, bv3 = -3e38f;
    int bi0 = 0, bi1 = 0, bi2 = 0, bi3 = 0;
    for (int q2 = 0; q2 < P2; ++q2) {
      const float v = logit[q2];
      if (v > bv0) { bv3=bv2; bi3=bi2; bv2=bv1; bi2=bi1; bv1=bv0; bi1=bi0; bv0=v; bi0=q2; }
      else if (v > bv1) { bv3=bv2; bi3=bi2; bv2=bv1; bi2=bi1; bv1=v; bi1=q2; }
      else if (v > bv2) { bv3=bv2; bi3=bi2; bv2=v; bi2=q2; }
      else if (v > bv3) { bv3=v; bi3=q2; }
    }
    int* rp = r_idx + (size_t)bidx * TOPK;
    rp[0] = bi0; rp[1] = bi1; rp[2] = bi2; rp[3] = bi3;
  }
}

// ---------------------------------------------------------------------------
// bf16 MFMA GEMM: C[M][*] = A[M][256] @ Bt[N][256]^T + bias
// 128x128 tile, BK=64, 4 waves, reg-staged LDS, repacked coalesced epilogue.
// MODE 0: bf16 out split into C0/C1/C2 by bn>>1 (QKV). MODE 1: fp32 out Cf.
// ---------------------------------------------------------------------------
template<int MODE>
__global__ __launch_bounds__(256) void gemm_mfma(
    const unsigned short* __restrict__ A,
    const unsigned short* __restrict__ Bt,
    const float* __restrict__ bias,
    unsigned short* __restrict__ C0, unsigned short* __restrict__ C1,
    unsigned short* __restrict__ C2, float* __restrict__ Cf)
{
  __shared__ char smem[32768];
  unsigned short* Asm = (unsigned short*)smem;            // [128][64] bf16
  unsigned short* Bsm = (unsigned short*)(smem + 16384);  // [128][64] bf16
  float* Cs = (float*)smem;                               // [64][128] f32 (reuse)

  const int t = threadIdx.x;
  const int w = t >> 6, l = t & 63;
  const int wr = w >> 1, wc = w & 1;
  const int lr = l & 15, lg = l >> 4;
  const int bm = blockIdx.x, bn = blockIdx.y;
  const int row0 = bm * 128, col0 = bn * 128;

  const f32x4 fzero = {0.f, 0.f, 0.f, 0.f};
  f32x4 acc[4][4];
  #pragma unroll
  for (int m = 0; m < 4; ++m)
    #pragma unroll
    for (int n = 0; n < 4; ++n) acc[m][n] = fzero;

  const int srow = t >> 3, skoff = (t & 7) * 8;
  bf16x8 ra[4], rb[4];
  #pragma unroll
  for (int i = 0; i < 4; ++i) {
    ra[i] = *(const bf16x8*)&A [(size_t)(row0 + i*32 + srow) * 256 + skoff];
    rb[i] = *(const bf16x8*)&Bt[(size_t)(col0 + i*32 + srow) * 256 + skoff];
  }

  for (int step = 0; step < 4; ++step) {
    __syncthreads();
    #pragma unroll
    for (int i = 0; i < 4; ++i) {
      *(bf16x8*)&Asm[(i*32 + srow) * 64 + skoff] = ra[i];
      *(bf16x8*)&Bsm[(i*32 + srow) * 64 + skoff] = rb[i];
    }
    __syncthreads();
    if (step < 3) {
      const int k1 = (step + 1) * 64;
      #pragma unroll
      for (int i = 0; i < 4; ++i) {
        ra[i] = *(const bf16x8*)&A [(size_t)(row0 + i*32 + srow) * 256 + k1 + skoff];
        rb[i] = *(const bf16x8*)&Bt[(size_t)(col0 + i*32 + srow) * 256 + k1 + skoff];
      }
    }
    #pragma unroll
    for (int kk = 0; kk < 2; ++kk) {
      bf16x8 af[4], bb[4];
      #pragma unroll
      for (int m = 0; m < 4; ++m)
        af[m] = *(const bf16x8*)&Asm[(wr*64 + m*16 + lr) * 64 + kk*32 + lg*8];
      #pragma unroll
      for (int n = 0; n < 4; ++n)
        bb[n] = *(const bf16x8*)&Bsm[(wc*64 + n*16 + lr) * 64 + kk*32 + lg*8];
      #pragma unroll
      for (int m = 0; m < 4; ++m)
        #pragma unroll
        for (int n = 0; n < 4; ++n)
          acc[m][n] = __builtin_amdgcn_mfma_f32_16x16x32_bf16(af[m], bb[n], acc[m][n], 0, 0, 0);
    }
  }

  float bcol[4];
  #pragma unroll
  for (int n = 0; n < 4; ++n) bcol[n] = bias[col0 + wc*64 + n*16 + lr];

  #pragma unroll
  for (int hf = 0; hf < 2; ++hf) {
    __syncthreads();
    if (wr == hf) {
      #pragma unroll
      for (int m = 0; m < 4; ++m)
        #pragma unroll
        for (int n = 0; n < 4; ++n)
          #pragma unroll
          for (int r = 0; r < 4; ++r) {
            const int lrow = m*16 + lg*4 + r;           // 0..63
            const int col  = wc*64 + n*16 + lr;         // 0..127
            const int csw  = col ^ ((lrow & 7) << 2);
            Cs[lrow * 128 + csw] = acc[m][n][r] + bcol[n];
          }
    }
    __syncthreads();
    #pragma unroll
    for (int it = 0; it < 8; ++it) {
      const int d = (it * 256 + t) * 4;
      const int lrow = d >> 7;
      const int colL = (d & 127) ^ ((lrow & 7) << 2);
      f32x4 v = *(const f32x4*)&Cs[d];
      const size_t grow = (size_t)(row0 + hf*64 + lrow);
      if (MODE == 0) {
        unsigned short* Cp = (bn < 2) ? C0 : (bn < 4) ? C1 : C2;
        const int lc = (bn & 1) * 128 + colL;
        ushort4 o = { f2bf(v[0]), f2bf(v[1]), f2bf(v[2]), f2bf(v[3]) };
        *(ushort4*)&Cp[grow * 256 + lc] = o;
      } else {
        float4 o = { v[0], v[1], v[2], v[3] };
        *(float4*)&Cf[grow * 256 + (size_t)(bn * 128) + colL] = o;
      }
    }
  }
}

// ---------------------------------------------------------------------------
// MFMA gathered attention. grid = N*P2*HEADS (b&7 = head), 256 threads / 4 waves.
// ---------------------------------------------------------------------------
#define KPAD 40      // K/Q row stride (elems) = 80B
#define PSTR 264     // P/VT row stride (elems) = 528B

__global__ __launch_bounds__(256) void attn_mfma(
    const unsigned short* __restrict__ q_bf,
    const unsigned short* __restrict__ k_bf,
    const unsigned short* __restrict__ v_bf,
    const int* __restrict__ r_idx,
    unsigned short* __restrict__ o_bf)
{
  __shared__ char smem[76288];
  unsigned short* Ksm = (unsigned short*)smem;              // [256][KPAD]
  unsigned short* Vsm = (unsigned short*)(smem + 20480);    // [32][PSTR]  (V^T)
  unsigned short* Qsm = (unsigned short*)(smem + 37376);    // [64][KPAD]
  unsigned short* Psm = (unsigned short*)(smem + 42496);    // [64][PSTR]
  float* Osm = (float*)smem;                                // [64][36] f32 (over Ksm)

  const int b = blockIdx.x;
  const int h = b & 7;
  const int np = b >> 3;
  const int n = np / P2, p = np - n * P2;
  const int t = threadIdx.x;
  const int w = t >> 6, l = t & 63;
  const int lr = l & 15, lg = l >> 4;

  // ---- stage K (row-major, padded) and V^T ----
  {
    const int wv = r_idx[np * 4 + (t >> 6)];
    const int pix = t & 63;
    const int ky = (wv / NWIN) * 8 + (pix >> 3);
    const int kx = (wv % NWIN) * 8 + (pix & 7);
    const size_t goff = ((size_t)((n * HWDIM + ky) * HWDIM + kx)) * 256 + h * 32;
    #pragma unroll
    for (int j = 0; j < 4; ++j) {
      bf16x8 kv = *(const bf16x8*)&k_bf[goff + j * 8];
      *(bf16x8*)&Ksm[t * KPAD + j * 8] = kv;
      bf16x8 vv = *(const bf16x8*)&v_bf[goff + j * 8];
      #pragma unroll
      for (int e = 0; e < 8; ++e)
        Vsm[(j * 8 + e) * PSTR + t] = (unsigned short)vv[e];
    }
  }
  // ---- stage Q ----
  {
    const int qr = t >> 2, jq = t & 3;
    const int qy = (p / NWIN) * 8 + (qr >> 3);
    const int qx = (p % NWIN) * 8 + (qr & 7);
    *(bf16x8*)&Qsm[qr * KPAD + jq * 8] =
        *(const bf16x8*)&q_bf[((size_t)((n * HWDIM + qy) * HWDIM + qx)) * 256 + h * 32 + jq * 8];
  }
  __syncthreads();

  // ---- QK^T : wave w owns q rows [w*16, w*16+16) ----
  f32x4 sf[16];
  {
    const f32x4 fzero = {0.f, 0.f, 0.f, 0.f};
    bf16x8 aq = *(const bf16x8*)&Qsm[(w * 16 + lr) * KPAD + lg * 8];
    #pragma unroll
    for (int f = 0; f < 16; ++f) {
      bf16x8 bk = *(const bf16x8*)&Ksm[(f * 16 + lr) * KPAD + lg * 8];
      sf[f] = __builtin_amdgcn_mfma_f32_16x16x32_bf16(aq, bk, fzero, 0, 0, 0);
    }
  }

  // ---- softmax ----
  float inv[4];
  #pragma unroll
  for (int r = 0; r < 4; ++r) {
    float mx = sf[0][r];
    #pragma unroll
    for (int f = 1; f < 16; ++f) mx = fmaxf(mx, sf[f][r]);
    mx = fmaxf(mx, __shfl_xor(mx, 1));
    mx = fmaxf(mx, __shfl_xor(mx, 2));
    mx = fmaxf(mx, __shfl_xor(mx, 4));
    mx = fmaxf(mx, __shfl_xor(mx, 8));
    float sum = 0.f;
    #pragma unroll
    for (int f = 0; f < 16; ++f) { float e = __expf(sf[f][r] - mx); sf[f][r] = e; sum += e; }
    sum += __shfl_xor(sum, 1);
    sum += __shfl_xor(sum, 2);
    sum += __shfl_xor(sum, 4);
    sum += __shfl_xor(sum, 8);
    inv[r] = 1.f / sum;
  }
  #pragma unroll
  for (int f = 0; f < 16; ++f)
    #pragma unroll
    for (int r = 0; r < 4; ++r) {
      const int q = w * 16 + lg * 4 + r;
      const int key = f * 16 + lr;
      const int blk = (key >> 3) ^ (q & 7);
      Psm[q * PSTR + blk * 8 + (key & 7)] = f2bf(sf[f][r] * inv[r]);
    }
  __syncthreads();

  // ---- PV ----
  f32x4 oacc[2];
  oacc[0] = (f32x4){0.f, 0.f, 0.f, 0.f};
  oacc[1] = (f32x4){0.f, 0.f, 0.f, 0.f};
  #pragma unroll
  for (int ks = 0; ks < 8; ++ks) {
    const int ablk = (ks * 4 + lg) ^ (lr & 7);
    bf16x8 ap = *(const bf16x8*)&Psm[(w * 16 + lr) * PSTR + ablk * 8];
    #pragma unroll
    for (int nn = 0; nn < 2; ++nn) {
      bf16x8 bv = *(const bf16x8*)&Vsm[(nn * 16 + lr) * PSTR + ks * 32 + lg * 8];
      oacc[nn] = __builtin_amdgcn_mfma_f32_16x16x32_bf16(ap, bv, oacc[nn], 0, 0, 0);
    }
  }

  // ---- repack + store ----
  #pragma unroll
  for (int nn = 0; nn < 2; ++nn)
    #pragma unroll
    for (int r = 0; r < 4; ++r)
      Osm[(w * 16 + lg * 4 + r) * 36 + nn * 16 + lr] = oacc[nn][r];
  __syncthreads();
  {
    const int q = t >> 2, dq = (t & 3) * 8;
    const int qy = (p / NWIN) * 8 + (q >> 3);
    const int qx = (p % NWIN) * 8 + (q & 7);
    float vo[8];
    #pragma unroll
    for (int e = 0; e < 8; ++e) vo[e] = Osm[q * 36 + dq + e];
    ushort4 o0 = { f2bf(vo[0]), f2bf(vo[1]), f2bf(vo[2]), f2bf(vo[3]) };
    ushort4 o1 = { f2bf(vo[4]), f2bf(vo[5]), f2bf(vo[6]), f2bf(vo[7]) };
    unsigned short* op = &o_bf[((size_t)((n * HWDIM + qy) * HWDIM + qx)) * 256 + h * 32 + dq];
    *(ushort4*)op = o0;
    *(ushort4*)&op[4] = o1;
  }
}

// ---------------------------------------------------------------------------
// LEPE v2: thread = (pixel, 8-ch group). grid = 25088*32/256 = 3136 blocks.
// Wc is [25][256] fp32 (L1-resident). Coalesced 16B v loads, fp32 accum,
// bf16 RMW into attn output.
// ---------------------------------------------------------------------------
__global__ __launch_bounds__(256) void lepe_add(
    const unsigned short* __restrict__ v_bf, const float* __restrict__ Wc,
    const float* __restrict__ bias, unsigned short* __restrict__ o_bf)
{
  const int gid = blockIdx.x * 256 + threadIdx.x;
  const int c8 = (gid & 31) * 8;
  const int pix = gid >> 5;
  const int n = pix / (HWDIM * HWDIM);
  const int rem = pix - n * (HWDIM * HWDIM);
  const int y = rem / HWDIM, x = rem - y * HWDIM;

  float acc[8];
  {
    float4 b0 = *(const float4*)&bias[c8];
    float4 b1 = *(const float4*)&bias[c8 + 4];
    acc[0]=b0.x; acc[1]=b0.y; acc[2]=b0.z; acc[3]=b0.w;
    acc[4]=b1.x; acc[5]=b1.y; acc[6]=b1.z; acc[7]=b1.w;
  }

  #pragma unroll
  for (int ky = 0; ky < 5; ++ky) {
    const int sy = y + ky - 2;
    if (sy < 0 || sy >= HWDIM) continue;
    #pragma unroll
    for (int kx = 0; kx < 5; ++kx) {
      const int sx = x + kx - 2;
      if (sx < 0 || sx >= HWDIM) continue;
      const bf16x8 vv = *(const bf16x8*)&v_bf[((size_t)((n * HWDIM + sy) * HWDIM + sx)) * 256 + c8];
      const float* wp = &Wc[(ky * 5 + kx) * 256 + c8];
      float4 w0 = *(const float4*)wp;
      float4 w1 = *(const float4*)(wp + 4);
      acc[0] = fmaf(w0.x, bf2f((unsigned short)vv[0]), acc[0]);
      acc[1] = fmaf(w0.y, bf2f((unsigned short)vv[1]), acc[1]);
      acc[2] = fmaf(w0.z, bf2f((unsigned short)vv[2]), acc[2]);
      acc[3] = fmaf(w0.w, bf2f((unsigned short)vv[3]), acc[3]);
      acc[4] = fmaf(w1.x, bf2f((unsigned short)vv[4]), acc[4]);
      acc[5] = fmaf(w1.y, bf2f((unsigned short)vv[5]), acc[5]);
      acc[6] = fmaf(w1.z, bf2f((unsigned short)vv[6]), acc[6]);
      acc[7] = fmaf(w1.w, bf2f((unsigned short)vv[7]), acc[7]);
    }
  }

  unsigned short* op = &o_bf[(size_t)pix * 256 + c8];
  const bf16x8 ov = *(const bf16x8*)op;
  ushort4 o0 = { f2bf(bf2f((unsigned short)ov[0]) + acc[0]),
                 f2bf(bf2f((unsigned short)ov[1]) + acc[1]),
                 f2bf(bf2f((unsigned short)ov[2]) + acc[2]),
                 f2bf(bf2f((unsigned short)ov[3]) + acc[3]) };
  ushort4 o1 = { f2bf(bf2f((unsigned short)ov[4]) + acc[4]),
                 f2bf(bf2f((unsigned short)ov[5]) + acc[5]),
                 f2bf(bf2f((unsigned short)ov[6]) + acc[6]),
                 f2bf(bf2f((unsigned short)ov[7]) + acc[7]) };
  *(ushort4*)op = o0;
  *(ushort4*)(op + 4) = o1;
}

// ---------------------------------------------------------------------------
extern "C" void kernel_launch(void* const* d_in, const int* in_sizes, int n_in,
                              void* d_out, int out_size, void* d_ws, size_t ws_size,
                              hipStream_t stream)
{
  const float* x      = (const float*)d_in[0];
  const float* W_qkv  = (const float*)d_in[1];
  const float* b_qkv  = (const float*)d_in[2];
  const float* lepe_w = (const float*)d_in[3];
  const float* lepe_b = (const float*)d_in[4];
  const float* W_o    = (const float*)d_in[5];
  const float* b_o    = (const float*)d_in[6];
  float* out = (float*)d_out;

  char* ws = (char*)d_ws;
  const size_t IMG = (size_t)NPIX * 256;          // elems per image buffer
  unsigned short* x_bf    = (unsigned short*)(ws);
  unsigned short* q_bf    = (unsigned short*)(ws + 2*IMG);
  unsigned short* k_bf    = (unsigned short*)(ws + 4*IMG);
  unsigned short* v_bf    = (unsigned short*)(ws + 6*IMG);
  unsigned short* attn_bf = (unsigned short*)(ws + 8*IMG);
  unsigned short* Wt_qkv  = (unsigned short*)(ws + 10*IMG);
  unsigned short* Wt_o    = (unsigned short*)(ws + 10*IMG + 393216);
  float*          b_s     = (float*)         (ws + 10*IMG + 393216 + 131072);
  float*          x_win   = (float*)         (ws + 10*IMG + 393216 + 131072 + 4096);
  float*          q_win   = x_win + (size_t)NBATCH * P2 * 256;
  float*          k_win   = q_win + (size_t)NBATCH * P2 * 256;
  int*            ridx    = (int*)(k_win + (size_t)NBATCH * P2 * 256);
  float*          Wc      = (float*)(ridx + (size_t)NBATCH * P2 * TOPK);

  convert_x<<<3136, 256, 0, stream>>>(x, x_bf);
  prep_w<<<1052, 256, 0, stream>>>(W_qkv, b_qkv, W_o, lepe_w, Wt_qkv, Wt_o, b_s, Wc);
  x_win_kernel<<<NBATCH * P2, 256, 0, stream>>>(x, x_win);
  win_gemm<<<NBATCH * P2, 256, 0, stream>>>(x_win, W_qkv, b_qkv, q_win, k_win);
  routing_topk<<<NBATCH * P2, 256, 0, stream>>>(q_win, k_win, ridx);
  gemm_mfma<0><<<dim3(196, 6), 256, 0, stream>>>(x_bf, Wt_qkv, b_s,
                                                 q_bf, k_bf, v_bf, nullptr);
  attn_mfma<<<NBATCH * P2 * HEADS, 256, 0, stream>>>(q_bf, k_bf, v_bf, ridx, attn_bf);
  lepe_add<<<3136, 256, 0, stream>>>(v_bf, Wc, lepe_b, attn_bf);
  gemm_mfma<1><<<dim3(196, 2), 256, 0, stream>>>(attn_bf, Wt_o, b_o,
                                                 nullptr, nullptr, nullptr, out);
}

// Round 5
// 219.229 us; speedup vs baseline: 2.7327x; 1.0881x over previous
//
#include <hip/hip_runtime.h>
#include <hip/hip_bf16.h>
#include <math.h>

#define NBATCH 8
#define HWDIM  56
#define NWIN   7
#define P2     49
#define HEADS  8
#define TOPK   4
#define SCALE  0.0625f
#define NPIX   (NBATCH*HWDIM*HWDIM)   // 25088

typedef __attribute__((ext_vector_type(8))) short bf16x8;
typedef __attribute__((ext_vector_type(4))) float f32x4;

#define GLOBAL_AS __attribute__((address_space(1)))
#define LDS_AS    __attribute__((address_space(3)))

__device__ __forceinline__ void gload16(const unsigned short* g, unsigned short* l) {
  __builtin_amdgcn_global_load_lds((const GLOBAL_AS unsigned int*)g,
                                   (LDS_AS unsigned int*)l, 16, 0, 0);
}

__device__ __forceinline__ unsigned short f2bf(float f) {
  __hip_bfloat16 h = __float2bfloat16(f);
  return *reinterpret_cast<unsigned short*>(&h);
}
__device__ __forceinline__ float bf2f(unsigned short h) {
  return __uint_as_float(((unsigned)h) << 16);
}

// ---------------------------------------------------------------------------
// x (fp32) -> x_bf (bf16), 8 elems/thread
// ---------------------------------------------------------------------------
__global__ __launch_bounds__(256) void convert_x(
    const float* __restrict__ xin, unsigned short* __restrict__ xb)
{
  const int i = (blockIdx.x * 256 + threadIdx.x) * 8;
  float4 a = *(const float4*)&xin[i];
  float4 b = *(const float4*)&xin[i + 4];
  ushort4 o0 = { f2bf(a.x), f2bf(a.y), f2bf(a.z), f2bf(a.w) };
  ushort4 o1 = { f2bf(b.x), f2bf(b.y), f2bf(b.z), f2bf(b.w) };
  *(ushort4*)&xb[i] = o0;
  *(ushort4*)&xb[i + 4] = o1;
}

// ---------------------------------------------------------------------------
// Weight prep (transpose to [n][k], bf16; scaled q; lepe w -> [tap][c])
// ---------------------------------------------------------------------------
__global__ __launch_bounds__(256) void prep_w(
    const float* __restrict__ W_qkv, const float* __restrict__ b_qkv,
    const float* __restrict__ W_o, const float* __restrict__ lepe_w,
    unsigned short* __restrict__ Wt_qkv, unsigned short* __restrict__ Wt_o,
    float* __restrict__ b_s, float* __restrict__ Wc)
{
  const int idx = blockIdx.x * 256 + threadIdx.x;
  if (idx < 768 * 256) {
    const int nn = idx >> 8, cc = idx & 255;
    float v = W_qkv[cc * 768 + nn];
    if (nn < 256) v *= SCALE;
    Wt_qkv[idx] = f2bf(v);
  } else if (idx < 768 * 256 + 256 * 256) {
    const int j = idx - 768 * 256;
    const int nn = j >> 8, cc = j & 255;
    Wt_o[j] = f2bf(W_o[cc * 256 + nn]);
  } else if (idx < 768 * 256 + 256 * 256 + 768) {
    const int j = idx - (768 * 256 + 256 * 256);
    b_s[j] = b_qkv[j] * (j < 256 ? SCALE : 1.f);
  } else if (idx < 768 * 256 + 256 * 256 + 768 + 25 * 256) {
    const int j = idx - (768 * 256 + 256 * 256 + 768);
    const int tap = j >> 8, cc = j & 255;
    Wc[j] = lepe_w[cc * 25 + tap];
  }
}

// ---------------------------------------------------------------------------
// Window means of x (fp32, exact routing path). grid = N*P2, float4 loads.
// ---------------------------------------------------------------------------
__global__ __launch_bounds__(256) void x_win_kernel(
    const float* __restrict__ x, float* __restrict__ xw)
{
  __shared__ float4 red[256];
  const int bidx = blockIdx.x;
  const int n = bidx / P2, p = bidx - n * P2;
  const int y0 = (p / NWIN) * 8, x0 = (p % NWIN) * 8;
  const int t = threadIdx.x;
  const int c4 = t & 63, pg = t >> 6;
  float4 s = {0.f, 0.f, 0.f, 0.f};
  #pragma unroll
  for (int k = 0; k < 16; ++k) {
    const int pix = pg * 16 + k;
    const int yy = y0 + (pix >> 3), xx = x0 + (pix & 7);
    float4 v = *(const float4*)&x[((size_t)((n * HWDIM + yy) * HWDIM + xx)) * 256 + c4 * 4];
    s.x += v.x; s.y += v.y; s.z += v.z; s.w += v.w;
  }
  red[t] = s;
  __syncthreads();
  if (pg == 0) {
    float4 a = red[c4], b = red[64 + c4], c = red[128 + c4], d = red[192 + c4];
    float4 o = { (a.x + b.x + c.x + d.x) * (1.f/64.f),
                 (a.y + b.y + c.y + d.y) * (1.f/64.f),
                 (a.z + b.z + c.z + d.z) * (1.f/64.f),
                 (a.w + b.w + c.w + d.w) * (1.f/64.f) };
    *(float4*)&xw[(size_t)bidx * 256 + c4 * 4] = o;
  }
}

// ---------------------------------------------------------------------------
// q_win/k_win = x_win @ W_qkv[:, :512] + b (fp32 exact). grid = N*P2
// ---------------------------------------------------------------------------
__global__ __launch_bounds__(256) void win_gemm(
    const float* __restrict__ xw, const float* __restrict__ W_qkv,
    const float* __restrict__ b_qkv,
    float* __restrict__ q_win, float* __restrict__ k_win)
{
  __shared__ float xs[256];
  const int bidx = blockIdx.x;
  const int t = threadIdx.x;
  xs[t] = xw[(size_t)bidx * 256 + t];
  __syncthreads();
  float aq = 0.f, ak = 0.f;
  for (int cc = 0; cc < 256; ++cc) {
    const float xv = xs[cc];
    aq = fmaf(xv, W_qkv[cc * 768 + t], aq);
    ak = fmaf(xv, W_qkv[cc * 768 + 256 + t], ak);
  }
  q_win[(size_t)bidx * 256 + t] = aq + b_qkv[t];
  k_win[(size_t)bidx * 256 + t] = ak + b_qkv[256 + t];
}

// ---------------------------------------------------------------------------
// Routing: grid = N*P2 blocks; 4 lanes x 64ch partials per logit;
// top-4 scan of 49 by lane 0 (fp32 exact).
// ---------------------------------------------------------------------------
__global__ __launch_bounds__(256) void routing_topk(
    const float* __restrict__ q_win, const float* __restrict__ k_win,
    int* __restrict__ r_idx)
{
  __shared__ float qs[256];
  __shared__ float logit[64];
  const int bidx = blockIdx.x;
  const int n = bidx / P2;
  const int t = threadIdx.x;
  qs[t] = q_win[(size_t)bidx * 256 + t];
  __syncthreads();
  const int qq = t >> 2, qt = t & 3;
  if (qq < P2) {
    const float* kb = k_win + ((size_t)(n * P2 + qq)) * 256 + qt * 64;
    float a = 0.f;
    #pragma unroll 8
    for (int i = 0; i < 64; ++i) a = fmaf(qs[qt * 64 + i], kb[i], a);
    a += __shfl_xor(a, 1);
    a += __shfl_xor(a, 2);
    if (qt == 0) logit[qq] = a;
  }
  __syncthreads();
  if (t == 0) {
    float bv0 = -3e38f, bv1 = -3e38f, bv2 = -3e38f, bv3 = -3e38f;
    int bi0 = 0, bi1 = 0, bi2 = 0, bi3 = 0;
    for (int q2 = 0; q2 < P2; ++q2) {
      const float v = logit[q2];
      if (v > bv0) { bv3=bv2; bi3=bi2; bv2=bv1; bi2=bi1; bv1=bv0; bi1=bi0; bv0=v; bi0=q2; }
      else if (v > bv1) { bv3=bv2; bi3=bi2; bv2=bv1; bi2=bi1; bv1=v; bi1=q2; }
      else if (v > bv2) { bv3=bv2; bi3=bi2; bv2=v; bi2=q2; }
      else if (v > bv3) { bv3=v; bi3=q2; }
    }
    int* rp = r_idx + (size_t)bidx * TOPK;
    rp[0] = bi0; rp[1] = bi1; rp[2] = bi2; rp[3] = bi3;
  }
}

// ---------------------------------------------------------------------------
// bf16 MFMA GEMM, global_load_lds staging (linear LDS, source-side XOR swizzle).
// 128x128 tile, BK=64, 4 waves, single-buffer (occupancy 5 blocks/CU).
// MODE 0: bf16 out split into C0/C1/C2 by bn>>1 (QKV). MODE 1: fp32 out Cf.
// ---------------------------------------------------------------------------
template<int MODE>
__global__ __launch_bounds__(256) void gemm_mfma(
    const unsigned short* __restrict__ A,
    const unsigned short* __restrict__ Bt,
    const float* __restrict__ bias,
    unsigned short* __restrict__ C0, unsigned short* __restrict__ C1,
    unsigned short* __restrict__ C2, float* __restrict__ Cf)
{
  __shared__ char smem[32768];
  unsigned short* Asm = (unsigned short*)smem;            // [128][64] bf16 (k-chunk XOR'ed)
  unsigned short* Bsm = (unsigned short*)(smem + 16384);  // [128][64] bf16
  float* Cs = (float*)smem;                               // [64][128] f32 (reuse)

  const int t = threadIdx.x;
  const int w = t >> 6, l = t & 63;
  const int wr = w >> 1, wc = w & 1;
  const int lr = l & 15, lg = l >> 4;
  const int bm = blockIdx.x, bn = blockIdx.y;
  const int row0 = bm * 128, col0 = bn * 128;

  const f32x4 fzero = {0.f, 0.f, 0.f, 0.f};
  f32x4 acc[4][4];
  #pragma unroll
  for (int m = 0; m < 4; ++m)
    #pragma unroll
    for (int n = 0; n < 4; ++n) acc[m][n] = fzero;

  // staging map: thread t -> LDS bytes [t*16, t*16+16) of chunk i.
  // logical (row = i*32 + t>>3, k-chunk pos = t&7 holds chunk (t&7)^(row&7)).
  const int srow  = t >> 3;
  const int skoff = ((t & 7) ^ (srow & 7)) * 8;   // pre-swizzled global k offset

  for (int step = 0; step < 4; ++step) {
    const int k0 = step * 64;
    #pragma unroll
    for (int i = 0; i < 4; ++i) {
      gload16(&A [(size_t)(row0 + i*32 + srow) * 256 + k0 + skoff], Asm + i*2048 + t*8);
      gload16(&Bt[(size_t)(col0 + i*32 + srow) * 256 + k0 + skoff], Bsm + i*2048 + t*8);
    }
    __syncthreads();   // drains vmcnt -> tiles ready
    #pragma unroll
    for (int kk = 0; kk < 2; ++kk) {
      bf16x8 af[4], bb[4];
      #pragma unroll
      for (int m = 0; m < 4; ++m)
        af[m] = *(const bf16x8*)&Asm[(wr*64 + m*16 + lr) * 64 + ((kk*4 + lg) ^ (lr & 7)) * 8];
      #pragma unroll
      for (int n = 0; n < 4; ++n)
        bb[n] = *(const bf16x8*)&Bsm[(wc*64 + n*16 + lr) * 64 + ((kk*4 + lg) ^ (lr & 7)) * 8];
      #pragma unroll
      for (int m = 0; m < 4; ++m)
        #pragma unroll
        for (int n = 0; n < 4; ++n)
          acc[m][n] = __builtin_amdgcn_mfma_f32_16x16x32_bf16(af[m], bb[n], acc[m][n], 0, 0, 0);
    }
    __syncthreads();   // protect LDS before next-step staging overwrites
  }

  float bcol[4];
  #pragma unroll
  for (int n = 0; n < 4; ++n) bcol[n] = bias[col0 + wc*64 + n*16 + lr];

  #pragma unroll
  for (int hf = 0; hf < 2; ++hf) {
    if (hf) __syncthreads();
    if (wr == hf) {
      #pragma unroll
      for (int m = 0; m < 4; ++m)
        #pragma unroll
        for (int n = 0; n < 4; ++n)
          #pragma unroll
          for (int r = 0; r < 4; ++r) {
            const int lrow = m*16 + lg*4 + r;           // 0..63
            const int col  = wc*64 + n*16 + lr;         // 0..127
            const int csw  = col ^ ((lrow & 7) << 2);
            Cs[lrow * 128 + csw] = acc[m][n][r] + bcol[n];
          }
    }
    __syncthreads();
    #pragma unroll
    for (int it = 0; it < 8; ++it) {
      const int d = (it * 256 + t) * 4;
      const int lrow = d >> 7;
      const int colL = (d & 127) ^ ((lrow & 7) << 2);
      f32x4 v = *(const f32x4*)&Cs[d];
      const size_t grow = (size_t)(row0 + hf*64 + lrow);
      if (MODE == 0) {
        unsigned short* Cp = (bn < 2) ? C0 : (bn < 4) ? C1 : C2;
        const int lc = (bn & 1) * 128 + colL;
        ushort4 o = { f2bf(v[0]), f2bf(v[1]), f2bf(v[2]), f2bf(v[3]) };
        *(ushort4*)&Cp[grow * 256 + lc] = o;
      } else {
        float4 o = { v[0], v[1], v[2], v[3] };
        *(float4*)&Cf[grow * 256 + (size_t)(bn * 128) + colL] = o;
      }
    }
  }
}

// ---------------------------------------------------------------------------
// MFMA gathered attention v2. grid = N*P2*HEADS, 256 threads / 4 waves.
// Swapped QK^T (S^T in-register) -> per-lane softmax -> packed b64 P writes
// (P overlays K+Q) -> PV -> deferred 1/l normalization -> LDS repack store.
// LDS 52.5 KB -> 3 blocks/CU.
// ---------------------------------------------------------------------------
#define PSTR 272     // P / V^T row stride in elems (544 B -> uniform bank slots)

__global__ __launch_bounds__(256) void attn_mfma(
    const unsigned short* __restrict__ q_bf,
    const unsigned short* __restrict__ k_bf,
    const unsigned short* __restrict__ v_bf,
    const int* __restrict__ r_idx,
    unsigned short* __restrict__ o_bf)
{
  __shared__ char smem[52480];
  unsigned short* Ksm = (unsigned short*)smem;              // [256][32] bf16
  unsigned short* Qsm = (unsigned short*)(smem + 16384);    // [64][32] bf16
  unsigned short* Psm = (unsigned short*)smem;              // [64][PSTR] (overlays K,Q)
  unsigned short* Vsm = (unsigned short*)(smem + 34816);    // [32][PSTR] (V^T)
  float*          Osm = (float*)(smem + 34816);             // [64][36] f32 (overlays V)
  float*          Ls  = (float*)(smem + 52224);             // [64] inv-sum

  const int b = blockIdx.x;
  const int h = b & 7;
  const int np = b >> 3;
  const int n = np / P2, p = np - n * P2;
  const int t = threadIdx.x;
  const int w = t >> 6, l = t & 63;
  const int lr = l & 15, lg = l >> 4;

  const int4 rv = *(const int4*)&r_idx[np * 4];

  // ---- stage K via global_load_lds (chunk i = window i, 64 rows x 64 B) ----
  {
    const int pix = t >> 2, ch = t & 3;
    #pragma unroll
    for (int i = 0; i < 4; ++i) {
      const int wv = (&rv.x)[i];
      const int ky = (wv / NWIN) * 8 + (pix >> 3);
      const int kx = (wv % NWIN) * 8 + (pix & 7);
      const size_t goff = ((size_t)((n * HWDIM + ky) * HWDIM + kx)) * 256 + h * 32;
      gload16(&k_bf[goff + ch * 8], Ksm + i * 2048 + t * 8);
    }
    // Q: 64 rows x 64 B in one shot
    const int qy = (p / NWIN) * 8 + (pix >> 3);
    const int qx = (p % NWIN) * 8 + (pix & 7);
    gload16(&q_bf[((size_t)((n * HWDIM + qy) * HWDIM + qx)) * 256 + h * 32 + ch * 8],
            Qsm + t * 8);
  }
  // ---- stage V^T (scalar transpose writes, col = key index t) ----
  {
    const int s = t >> 6, pix = t & 63;
    const int wv = (&rv.x)[s];
    const int ky = (wv / NWIN) * 8 + (pix >> 3);
    const int kx = (wv % NWIN) * 8 + (pix & 7);
    const size_t goff = ((size_t)((n * HWDIM + ky) * HWDIM + kx)) * 256 + h * 32;
    #pragma unroll
    for (int j = 0; j < 4; ++j) {
      bf16x8 vv = *(const bf16x8*)&v_bf[goff + j * 8];
      #pragma unroll
      for (int e = 0; e < 8; ++e)
        Vsm[(j * 8 + e) * PSTR + t] = (unsigned short)vv[e];
    }
  }
  __syncthreads();

  // ---- swapped QK^T: sf[f] = S^T[key block f][q = w*16+lr] ----
  f32x4 sf[16];
  {
    const f32x4 fzero = {0.f, 0.f, 0.f, 0.f};
    bf16x8 aq = *(const bf16x8*)&Qsm[(w * 16 + lr) * 32 + lg * 8];
    #pragma unroll
    for (int f = 0; f < 16; ++f) {
      bf16x8 bk = *(const bf16x8*)&Ksm[(f * 16 + lr) * 32 + lg * 8];
      sf[f] = __builtin_amdgcn_mfma_f32_16x16x32_bf16(bk, aq, fzero, 0, 0, 0);
    }
  }

  // ---- per-lane softmax over 64 in-lane keys + lg-combine (xor 16,32) ----
  {
    float mx = sf[0][0];
    #pragma unroll
    for (int f = 0; f < 16; ++f)
      #pragma unroll
      for (int r = 0; r < 4; ++r) mx = fmaxf(mx, sf[f][r]);
    mx = fmaxf(mx, __shfl_xor(mx, 16));
    mx = fmaxf(mx, __shfl_xor(mx, 32));
    float sum = 0.f;
    #pragma unroll
    for (int f = 0; f < 16; ++f)
      #pragma unroll
      for (int r = 0; r < 4; ++r) {
        float e = __expf(sf[f][r] - mx);
        sf[f][r] = e; sum += e;
      }
    sum += __shfl_xor(sum, 16);
    sum += __shfl_xor(sum, 32);
    if (lg == 0) Ls[w * 16 + lr] = 1.f / sum;
  }
  __syncthreads();   // all QK^T reads of K/Q done before P overlays them

  // ---- P write: unnormalized exp, 4 consecutive keys per b64 ----
  #pragma unroll
  for (int f = 0; f < 16; ++f) {
    ushort4 pk = { f2bf(sf[f][0]), f2bf(sf[f][1]), f2bf(sf[f][2]), f2bf(sf[f][3]) };
    *(ushort4*)&Psm[(w * 16 + lr) * PSTR + f * 16 + lg * 4] = pk;
  }

  // ---- PV: out[q][d] = P[q][:] . V[:, d]  (P self-wave, no barrier) ----
  f32x4 oacc[2];
  oacc[0] = (f32x4){0.f, 0.f, 0.f, 0.f};
  oacc[1] = (f32x4){0.f, 0.f, 0.f, 0.f};
  #pragma unroll
  for (int ks = 0; ks < 8; ++ks) {
    bf16x8 ap = *(const bf16x8*)&Psm[(w * 16 + lr) * PSTR + ks * 32 + lg * 8];
    #pragma unroll
    for (int nn = 0; nn < 2; ++nn) {
      bf16x8 bv = *(const bf16x8*)&Vsm[(nn * 16 + lr) * PSTR + ks * 32 + lg * 8];
      oacc[nn] = __builtin_amdgcn_mfma_f32_16x16x32_bf16(ap, bv, oacc[nn], 0, 0, 0);
    }
  }

  float inv4[4];
  #pragma unroll
  for (int r = 0; r < 4; ++r) inv4[r] = Ls[w * 16 + lg * 4 + r];

  __syncthreads();   // all PV reads of V done before Osm overlays it
  #pragma unroll
  for (int nn = 0; nn < 2; ++nn)
    #pragma unroll
    for (int r = 0; r < 4; ++r)
      Osm[(w * 16 + lg * 4 + r) * 36 + nn * 16 + lr] = oacc[nn][r] * inv4[r];
  __syncthreads();
  {
    const int q = t >> 2, dq = (t & 3) * 8;
    const int qy = (p / NWIN) * 8 + (q >> 3);
    const int qx = (p % NWIN) * 8 + (q & 7);
    float vo[8];
    #pragma unroll
    for (int e = 0; e < 8; ++e) vo[e] = Osm[q * 36 + dq + e];
    ushort4 o0 = { f2bf(vo[0]), f2bf(vo[1]), f2bf(vo[2]), f2bf(vo[3]) };
    ushort4 o1 = { f2bf(vo[4]), f2bf(vo[5]), f2bf(vo[6]), f2bf(vo[7]) };
    unsigned short* op = &o_bf[((size_t)((n * HWDIM + qy) * HWDIM + qx)) * 256 + h * 32 + dq];
    *(ushort4*)op = o0;
    *(ushort4*)&op[4] = o1;
  }
}

// ---------------------------------------------------------------------------
// LEPE: thread = (pixel, 8-ch group). 3136 blocks. fp32 accum, bf16 RMW.
// ---------------------------------------------------------------------------
__global__ __launch_bounds__(256) void lepe_add(
    const unsigned short* __restrict__ v_bf, const float* __restrict__ Wc,
    const float* __restrict__ bias, unsigned short* __restrict__ o_bf)
{
  const int gid = blockIdx.x * 256 + threadIdx.x;
  const int c8 = (gid & 31) * 8;
  const int pix = gid >> 5;
  const int n = pix / (HWDIM * HWDIM);
  const int rem = pix - n * (HWDIM * HWDIM);
  const int y = rem / HWDIM, x = rem - y * HWDIM;

  float acc[8];
  {
    float4 b0 = *(const float4*)&bias[c8];
    float4 b1 = *(const float4*)&bias[c8 + 4];
    acc[0]=b0.x; acc[1]=b0.y; acc[2]=b0.z; acc[3]=b0.w;
    acc[4]=b1.x; acc[5]=b1.y; acc[6]=b1.z; acc[7]=b1.w;
  }

  #pragma unroll
  for (int ky = 0; ky < 5; ++ky) {
    const int sy = y + ky - 2;
    if (sy < 0 || sy >= HWDIM) continue;
    #pragma unroll
    for (int kx = 0; kx < 5; ++kx) {
      const int sx = x + kx - 2;
      if (sx < 0 || sx >= HWDIM) continue;
      const bf16x8 vv = *(const bf16x8*)&v_bf[((size_t)((n * HWDIM + sy) * HWDIM + sx)) * 256 + c8];
      const float* wp = &Wc[(ky * 5 + kx) * 256 + c8];
      float4 w0 = *(const float4*)wp;
      float4 w1 = *(const float4*)(wp + 4);
      acc[0] = fmaf(w0.x, bf2f((unsigned short)vv[0]), acc[0]);
      acc[1] = fmaf(w0.y, bf2f((unsigned short)vv[1]), acc[1]);
      acc[2] = fmaf(w0.z, bf2f((unsigned short)vv[2]), acc[2]);
      acc[3] = fmaf(w0.w, bf2f((unsigned short)vv[3]), acc[3]);
      acc[4] = fmaf(w1.x, bf2f((unsigned short)vv[4]), acc[4]);
      acc[5] = fmaf(w1.y, bf2f((unsigned short)vv[5]), acc[5]);
      acc[6] = fmaf(w1.z, bf2f((unsigned short)vv[6]), acc[6]);
      acc[7] = fmaf(w1.w, bf2f((unsigned short)vv[7]), acc[7]);
    }
  }

  unsigned short* op = &o_bf[(size_t)pix * 256 + c8];
  const bf16x8 ov = *(const bf16x8*)op;
  ushort4 o0 = { f2bf(bf2f((unsigned short)ov[0]) + acc[0]),
                 f2bf(bf2f((unsigned short)ov[1]) + acc[1]),
                 f2bf(bf2f((unsigned short)ov[2]) + acc[2]),
                 f2bf(bf2f((unsigned short)ov[3]) + acc[3]) };
  ushort4 o1 = { f2bf(bf2f((unsigned short)ov[4]) + acc[4]),
                 f2bf(bf2f((unsigned short)ov[5]) + acc[5]),
                 f2bf(bf2f((unsigned short)ov[6]) + acc[6]),
                 f2bf(bf2f((unsigned short)ov[7]) + acc[7]) };
  *(ushort4*)op = o0;
  *(ushort4*)(op + 4) = o1;
}

// ---------------------------------------------------------------------------
extern "C" void kernel_launch(void* const* d_in, const int* in_sizes, int n_in,
                              void* d_out, int out_size, void* d_ws, size_t ws_size,
                              hipStream_t stream)
{
  const float* x      = (const float*)d_in[0];
  const float* W_qkv  = (const float*)d_in[1];
  const float* b_qkv  = (const float*)d_in[2];
  const float* lepe_w = (const float*)d_in[3];
  const float* lepe_b = (const float*)d_in[4];
  const float* W_o    = (const float*)d_in[5];
  const float* b_o    = (const float*)d_in[6];
  float* out = (float*)d_out;

  char* ws = (char*)d_ws;
  const size_t IMG = (size_t)NPIX * 256;          // elems per image buffer
  unsigned short* x_bf    = (unsigned short*)(ws);
  unsigned short* q_bf    = (unsigned short*)(ws + 2*IMG);
  unsigned short* k_bf    = (unsigned short*)(ws + 4*IMG);
  unsigned short* v_bf    = (unsigned short*)(ws + 6*IMG);
  unsigned short* attn_bf = (unsigned short*)(ws + 8*IMG);
  unsigned short* Wt_qkv  = (unsigned short*)(ws + 10*IMG);
  unsigned short* Wt_o    = (unsigned short*)(ws + 10*IMG + 393216);
  float*          b_s     = (float*)         (ws + 10*IMG + 393216 + 131072);
  float*          x_win   = (float*)         (ws + 10*IMG + 393216 + 131072 + 4096);
  float*          q_win   = x_win + (size_t)NBATCH * P2 * 256;
  float*          k_win   = q_win + (size_t)NBATCH * P2 * 256;
  int*            ridx    = (int*)(k_win + (size_t)NBATCH * P2 * 256);
  float*          Wc      = (float*)(ridx + (size_t)NBATCH * P2 * TOPK);

  convert_x<<<3136, 256, 0, stream>>>(x, x_bf);
  prep_w<<<1052, 256, 0, stream>>>(W_qkv, b_qkv, W_o, lepe_w, Wt_qkv, Wt_o, b_s, Wc);
  x_win_kernel<<<NBATCH * P2, 256, 0, stream>>>(x, x_win);
  win_gemm<<<NBATCH * P2, 256, 0, stream>>>(x_win, W_qkv, b_qkv, q_win, k_win);
  routing_topk<<<NBATCH * P2, 256, 0, stream>>>(q_win, k_win, ridx);
  gemm_mfma<0><<<dim3(196, 6), 256, 0, stream>>>(x_bf, Wt_qkv, b_s,
                                                 q_bf, k_bf, v_bf, nullptr);
  attn_mfma<<<NBATCH * P2 * HEADS, 256, 0, stream>>>(q_bf, k_bf, v_bf, ridx, attn_bf);
  lepe_add<<<3136, 256, 0, stream>>>(v_bf, Wc, lepe_b, attn_bf);
  gemm_mfma<1><<<dim3(196, 2), 256, 0, stream>>>(attn_bf, Wt_o, b_o,
                                                 nullptr, nullptr, nullptr, out);
}

// Round 6
// 217.430 us; speedup vs baseline: 2.7553x; 1.0083x over previous
//
#include <hip/hip_runtime.h>
#include <hip/hip_bf16.h>
#include <math.h>

#define NBATCH 8
#define HWDIM  56
#define NWIN   7
#define P2     49
#define HEADS  8
#define TOPK   4
#define SCALE  0.0625f
#define NPIX   (NBATCH*HWDIM*HWDIM)   // 25088

typedef __attribute__((ext_vector_type(8))) short bf16x8;
typedef __attribute__((ext_vector_type(4))) float f32x4;

#define GLOBAL_AS __attribute__((address_space(1)))
#define LDS_AS    __attribute__((address_space(3)))

__device__ __forceinline__ void gload16(const unsigned short* g, unsigned short* l) {
  __builtin_amdgcn_global_load_lds((const GLOBAL_AS unsigned int*)g,
                                   (LDS_AS unsigned int*)l, 16, 0, 0);
}

__device__ __forceinline__ unsigned short f2bf(float f) {
  __hip_bfloat16 h = __float2bfloat16(f);
  return *reinterpret_cast<unsigned short*>(&h);
}
__device__ __forceinline__ float bf2f(unsigned short h) {
  return __uint_as_float(((unsigned)h) << 16);
}

// ---------------------------------------------------------------------------
// Fused: x (fp32) -> x_bf (bf16)  AND  per-window mean of x (fp32 routing path)
// grid = N*P2 (one block per window), 256 threads.
// ---------------------------------------------------------------------------
__global__ __launch_bounds__(256) void conv_xwin(
    const float* __restrict__ x, unsigned short* __restrict__ xb,
    float* __restrict__ xw)
{
  __shared__ float4 red[256];
  const int bidx = blockIdx.x;
  const int n = bidx / P2, p = bidx - n * P2;
  const int y0 = (p / NWIN) * 8, x0 = (p % NWIN) * 8;
  const int t = threadIdx.x;
  const int c4 = t & 63, pg = t >> 6;
  float4 s = {0.f, 0.f, 0.f, 0.f};
  #pragma unroll
  for (int k = 0; k < 16; ++k) {
    const int pix = pg * 16 + k;
    const int yy = y0 + (pix >> 3), xx = x0 + (pix & 7);
    const size_t off = ((size_t)((n * HWDIM + yy) * HWDIM + xx)) * 256 + c4 * 4;
    float4 v = *(const float4*)&x[off];
    ushort4 o = { f2bf(v.x), f2bf(v.y), f2bf(v.z), f2bf(v.w) };
    *(ushort4*)&xb[off] = o;
    s.x += v.x; s.y += v.y; s.z += v.z; s.w += v.w;
  }
  red[t] = s;
  __syncthreads();
  if (pg == 0) {
    float4 a = red[c4], b = red[64 + c4], c = red[128 + c4], d = red[192 + c4];
    float4 o = { (a.x + b.x + c.x + d.x) * (1.f/64.f),
                 (a.y + b.y + c.y + d.y) * (1.f/64.f),
                 (a.z + b.z + c.z + d.z) * (1.f/64.f),
                 (a.w + b.w + c.w + d.w) * (1.f/64.f) };
    *(float4*)&xw[(size_t)bidx * 256 + c4 * 4] = o;
  }
}

// ---------------------------------------------------------------------------
// Weight prep (transpose to [n][k], bf16; scaled q; lepe w -> [tap][c])
// ---------------------------------------------------------------------------
__global__ __launch_bounds__(256) void prep_w(
    const float* __restrict__ W_qkv, const float* __restrict__ b_qkv,
    const float* __restrict__ W_o, const float* __restrict__ lepe_w,
    unsigned short* __restrict__ Wt_qkv, unsigned short* __restrict__ Wt_o,
    float* __restrict__ b_s, float* __restrict__ Wc)
{
  const int idx = blockIdx.x * 256 + threadIdx.x;
  if (idx < 768 * 256) {
    const int nn = idx >> 8, cc = idx & 255;
    float v = W_qkv[cc * 768 + nn];
    if (nn < 256) v *= SCALE;
    Wt_qkv[idx] = f2bf(v);
  } else if (idx < 768 * 256 + 256 * 256) {
    const int j = idx - 768 * 256;
    const int nn = j >> 8, cc = j & 255;
    Wt_o[j] = f2bf(W_o[cc * 256 + nn]);
  } else if (idx < 768 * 256 + 256 * 256 + 768) {
    const int j = idx - (768 * 256 + 256 * 256);
    b_s[j] = b_qkv[j] * (j < 256 ? SCALE : 1.f);
  } else if (idx < 768 * 256 + 256 * 256 + 768 + 25 * 256) {
    const int j = idx - (768 * 256 + 256 * 256 + 768);
    const int tap = j >> 8, cc = j & 255;
    Wc[j] = lepe_w[cc * 25 + tap];
  }
}

// ---------------------------------------------------------------------------
// q_win/k_win = x_win @ W_qkv[:, :512] + b (fp32 exact). grid = N*P2
// ---------------------------------------------------------------------------
__global__ __launch_bounds__(256) void win_gemm(
    const float* __restrict__ xw, const float* __restrict__ W_qkv,
    const float* __restrict__ b_qkv,
    float* __restrict__ q_win, float* __restrict__ k_win)
{
  __shared__ float xs[256];
  const int bidx = blockIdx.x;
  const int t = threadIdx.x;
  xs[t] = xw[(size_t)bidx * 256 + t];
  __syncthreads();
  float aq = 0.f, ak = 0.f;
  for (int cc = 0; cc < 256; ++cc) {
    const float xv = xs[cc];
    aq = fmaf(xv, W_qkv[cc * 768 + t], aq);
    ak = fmaf(xv, W_qkv[cc * 768 + 256 + t], ak);
  }
  q_win[(size_t)bidx * 256 + t] = aq + b_qkv[t];
  k_win[(size_t)bidx * 256 + t] = ak + b_qkv[256 + t];
}

// ---------------------------------------------------------------------------
// Routing: grid = N*P2 blocks; 4 lanes x 64ch partials per logit;
// top-4 scan of 49 by lane 0 (fp32 exact).
// ---------------------------------------------------------------------------
__global__ __launch_bounds__(256) void routing_topk(
    const float* __restrict__ q_win, const float* __restrict__ k_win,
    int* __restrict__ r_idx)
{
  __shared__ float qs[256];
  __shared__ float logit[64];
  const int bidx = blockIdx.x;
  const int n = bidx / P2;
  const int t = threadIdx.x;
  qs[t] = q_win[(size_t)bidx * 256 + t];
  __syncthreads();
  const int qq = t >> 2, qt = t & 3;
  if (qq < P2) {
    const float* kb = k_win + ((size_t)(n * P2 + qq)) * 256 + qt * 64;
    float a = 0.f;
    #pragma unroll 8
    for (int i = 0; i < 64; ++i) a = fmaf(qs[qt * 64 + i], kb[i], a);
    a += __shfl_xor(a, 1);
    a += __shfl_xor(a, 2);
    if (qt == 0) logit[qq] = a;
  }
  __syncthreads();
  if (t == 0) {
    float bv0 = -3e38f, bv1 = -3e38f, bv2 = -3e38f, bv3 = -3e38f;
    int bi0 = 0, bi1 = 0, bi2 = 0, bi3 = 0;
    for (int q2 = 0; q2 < P2; ++q2) {
      const float v = logit[q2];
      if (v > bv0) { bv3=bv2; bi3=bi2; bv2=bv1; bi2=bi1; bv1=bv0; bi1=bi0; bv0=v; bi0=q2; }
      else if (v > bv1) { bv3=bv2; bi3=bi2; bv2=bv1; bi2=bi1; bv1=v; bi1=q2; }
      else if (v > bv2) { bv3=bv2; bi3=bi2; bv2=v; bi2=q2; }
      else if (v > bv3) { bv3=v; bi3=q2; }
    }
    int* rp = r_idx + (size_t)bidx * TOPK;
    rp[0] = bi0; rp[1] = bi1; rp[2] = bi2; rp[3] = bi3;
  }
}

// ---------------------------------------------------------------------------
// bf16 MFMA GEMM v2: 128x256 tile, BK=64, 512 threads / 8 waves (2x4),
// global_load_lds staging (linear LDS, source-side XOR swizzle).
// MODE 0: bf16 out -> C0/C1/C2 selected by bn (QKV, each 256 wide).
// MODE 1: fp32 out Cf (256 wide).
// ---------------------------------------------------------------------------
template<int MODE>
__global__ __launch_bounds__(512) void gemm_mfma(
    const unsigned short* __restrict__ A,
    const unsigned short* __restrict__ Bt,
    const float* __restrict__ bias,
    unsigned short* __restrict__ C0, unsigned short* __restrict__ C1,
    unsigned short* __restrict__ C2, float* __restrict__ Cf)
{
  __shared__ char smem[49152];
  unsigned short* Asm = (unsigned short*)smem;            // [128][64] bf16, chunk-XOR
  unsigned short* Bsm = (unsigned short*)(smem + 16384);  // [256][64] bf16, chunk-XOR
  float* Cs = (float*)smem;                               // [32][256] f32 (reuse)

  const int t = threadIdx.x;
  const int w = t >> 6, l = t & 63;
  const int wr = w >> 2, wc = w & 3;              // 2 x 4 wave grid
  const int lr = l & 15, lg = l >> 4;
  const int bm = blockIdx.x, bn = blockIdx.y;
  const int row0 = bm * 128, col0 = bn * 256;

  const f32x4 fzero = {0.f, 0.f, 0.f, 0.f};
  f32x4 acc[4][4];
  #pragma unroll
  for (int m = 0; m < 4; ++m)
    #pragma unroll
    for (int n = 0; n < 4; ++n) acc[m][n] = fzero;

  // staging map: thread t covers LDS bytes [t*16, t*16+16) of each 64-row chunk.
  // row-in-chunk = t>>3, stored k-chunk (t&7) holds global chunk (t&7)^(row&7).
  const int srow  = t >> 3;                        // 0..63
  const int skoff = ((t & 7) ^ (srow & 7)) * 8;    // pre-swizzled global k offset

  for (int step = 0; step < 4; ++step) {
    const int k0 = step * 64;
    #pragma unroll
    for (int i = 0; i < 2; ++i)
      gload16(&A [(size_t)(row0 + i*64 + srow) * 256 + k0 + skoff],
              Asm + i*4096 + t*8);
    #pragma unroll
    for (int i = 0; i < 4; ++i)
      gload16(&Bt[(size_t)(col0 + i*64 + srow) * 256 + k0 + skoff],
              Bsm + i*4096 + t*8);
    __syncthreads();   // drains vmcnt -> tiles ready
    #pragma unroll
    for (int kk = 0; kk < 2; ++kk) {
      bf16x8 af[4], bb[4];
      #pragma unroll
      for (int m = 0; m < 4; ++m)
        af[m] = *(const bf16x8*)&Asm[(wr*64 + m*16 + lr) * 64 + ((kk*4 + lg) ^ (lr & 7)) * 8];
      #pragma unroll
      for (int n = 0; n < 4; ++n)
        bb[n] = *(const bf16x8*)&Bsm[(wc*64 + n*16 + lr) * 64 + ((kk*4 + lg) ^ (lr & 7)) * 8];
      #pragma unroll
      for (int m = 0; m < 4; ++m)
        #pragma unroll
        for (int n = 0; n < 4; ++n)
          acc[m][n] = __builtin_amdgcn_mfma_f32_16x16x32_bf16(af[m], bb[n], acc[m][n], 0, 0, 0);
    }
    __syncthreads();   // protect LDS before next-step staging overwrites
  }

  float bcol[4];
  #pragma unroll
  for (int n = 0; n < 4; ++n) bcol[n] = bias[col0 + wc*64 + n*16 + lr];

  // epilogue: 4 quarters of 32 rows through LDS, coalesced stores
  #pragma unroll
  for (int hf = 0; hf < 4; ++hf) {
    if (hf) __syncthreads();
    if (wr == (hf >> 1)) {
      const int mbase = (hf & 1) * 2;
      #pragma unroll
      for (int mm = 0; mm < 2; ++mm)
        #pragma unroll
        for (int n = 0; n < 4; ++n)
          #pragma unroll
          for (int r = 0; r < 4; ++r) {
            const int lrow = mm*16 + lg*4 + r;          // 0..31 (quarter-local)
            const int col  = wc*64 + n*16 + lr;         // 0..255
            const int csw  = col ^ ((lrow & 7) << 2);
            Cs[lrow * 256 + csw] = acc[mbase + mm][n][r] + bcol[n];
          }
    }
    __syncthreads();
    #pragma unroll
    for (int it = 0; it < 4; ++it) {
      const int d = (it * 512 + t) * 4;
      const int lrow = d >> 8;
      const int colL = (d & 255) ^ ((lrow & 7) << 2);
      f32x4 v = *(const f32x4*)&Cs[d];
      const size_t grow = (size_t)(row0 + hf*32 + lrow);
      if (MODE == 0) {
        unsigned short* Cp = (bn == 0) ? C0 : (bn == 1) ? C1 : C2;
        ushort4 o = { f2bf(v[0]), f2bf(v[1]), f2bf(v[2]), f2bf(v[3]) };
        *(ushort4*)&Cp[grow * 256 + colL] = o;
      } else {
        float4 o = { v[0], v[1], v[2], v[3] };
        *(float4*)&Cf[grow * 256 + colL] = o;
      }
    }
  }
}

// ---------------------------------------------------------------------------
// MFMA gathered attention v2. grid = N*P2*HEADS, 256 threads / 4 waves.
// Swapped QK^T (S^T in-register) -> per-lane softmax -> packed b64 P writes
// (P overlays K+Q) -> PV -> deferred 1/l normalization -> LDS repack store.
// LDS 52.5 KB -> 3 blocks/CU.
// ---------------------------------------------------------------------------
#define PSTR 272     // P / V^T row stride in elems (544 B)

__global__ __launch_bounds__(256) void attn_mfma(
    const unsigned short* __restrict__ q_bf,
    const unsigned short* __restrict__ k_bf,
    const unsigned short* __restrict__ v_bf,
    const int* __restrict__ r_idx,
    unsigned short* __restrict__ o_bf)
{
  __shared__ char smem[52480];
  unsigned short* Ksm = (unsigned short*)smem;              // [256][32] bf16
  unsigned short* Qsm = (unsigned short*)(smem + 16384);    // [64][32] bf16
  unsigned short* Psm = (unsigned short*)smem;              // [64][PSTR] (overlays K,Q)
  unsigned short* Vsm = (unsigned short*)(smem + 34816);    // [32][PSTR] (V^T)
  float*          Osm = (float*)(smem + 34816);             // [64][36] f32 (overlays V)
  float*          Ls  = (float*)(smem + 52224);             // [64] inv-sum

  const int b = blockIdx.x;
  const int h = b & 7;
  const int np = b >> 3;
  const int n = np / P2, p = np - n * P2;
  const int t = threadIdx.x;
  const int w = t >> 6, l = t & 63;
  const int lr = l & 15, lg = l >> 4;

  const int4 rv = *(const int4*)&r_idx[np * 4];

  // ---- stage K via global_load_lds (chunk i = window i, 64 rows x 64 B) ----
  {
    const int pix = t >> 2, ch = t & 3;
    #pragma unroll
    for (int i = 0; i < 4; ++i) {
      const int wv = (&rv.x)[i];
      const int ky = (wv / NWIN) * 8 + (pix >> 3);
      const int kx = (wv % NWIN) * 8 + (pix & 7);
      const size_t goff = ((size_t)((n * HWDIM + ky) * HWDIM + kx)) * 256 + h * 32;
      gload16(&k_bf[goff + ch * 8], Ksm + i * 2048 + t * 8);
    }
    // Q: 64 rows x 64 B in one shot
    const int qy = (p / NWIN) * 8 + (pix >> 3);
    const int qx = (p % NWIN) * 8 + (pix & 7);
    gload16(&q_bf[((size_t)((n * HWDIM + qy) * HWDIM + qx)) * 256 + h * 32 + ch * 8],
            Qsm + t * 8);
  }
  // ---- stage V^T (scalar transpose writes, col = key index t) ----
  {
    const int s = t >> 6, pix = t & 63;
    const int wv = (&rv.x)[s];
    const int ky = (wv / NWIN) * 8 + (pix >> 3);
    const int kx = (wv % NWIN) * 8 + (pix & 7);
    const size_t goff = ((size_t)((n * HWDIM + ky) * HWDIM + kx)) * 256 + h * 32;
    #pragma unroll
    for (int j = 0; j < 4; ++j) {
      bf16x8 vv = *(const bf16x8*)&v_bf[goff + j * 8];
      #pragma unroll
      for (int e = 0; e < 8; ++e)
        Vsm[(j * 8 + e) * PSTR + t] = (unsigned short)vv[e];
    }
  }
  __syncthreads();

  // ---- swapped QK^T: sf[f] = S^T[key block f][q = w*16+lr] ----
  f32x4 sf[16];
  {
    const f32x4 fzero = {0.f, 0.f, 0.f, 0.f};
    bf16x8 aq = *(const bf16x8*)&Qsm[(w * 16 + lr) * 32 + lg * 8];
    #pragma unroll
    for (int f = 0; f < 16; ++f) {
      bf16x8 bk = *(const bf16x8*)&Ksm[(f * 16 + lr) * 32 + lg * 8];
      sf[f] = __builtin_amdgcn_mfma_f32_16x16x32_bf16(bk, aq, fzero, 0, 0, 0);
    }
  }

  // ---- per-lane softmax over 64 in-lane keys + lg-combine (xor 16,32) ----
  {
    float mx = sf[0][0];
    #pragma unroll
    for (int f = 0; f < 16; ++f)
      #pragma unroll
      for (int r = 0; r < 4; ++r) mx = fmaxf(mx, sf[f][r]);
    mx = fmaxf(mx, __shfl_xor(mx, 16));
    mx = fmaxf(mx, __shfl_xor(mx, 32));
    float sum = 0.f;
    #pragma unroll
    for (int f = 0; f < 16; ++f)
      #pragma unroll
      for (int r = 0; r < 4; ++r) {
        float e = __expf(sf[f][r] - mx);
        sf[f][r] = e; sum += e;
      }
    sum += __shfl_xor(sum, 16);
    sum += __shfl_xor(sum, 32);
    if (lg == 0) Ls[w * 16 + lr] = 1.f / sum;
  }
  __syncthreads();   // all QK^T reads of K/Q done before P overlays them

  // ---- P write: unnormalized exp, 4 consecutive keys per b64 ----
  #pragma unroll
  for (int f = 0; f < 16; ++f) {
    ushort4 pk = { f2bf(sf[f][0]), f2bf(sf[f][1]), f2bf(sf[f][2]), f2bf(sf[f][3]) };
    *(ushort4*)&Psm[(w * 16 + lr) * PSTR + f * 16 + lg * 4] = pk;
  }

  // ---- PV: out[q][d] = P[q][:] . V[:, d]  (P self-wave, no barrier) ----
  f32x4 oacc[2];
  oacc[0] = (f32x4){0.f, 0.f, 0.f, 0.f};
  oacc[1] = (f32x4){0.f, 0.f, 0.f, 0.f};
  #pragma unroll
  for (int ks = 0; ks < 8; ++ks) {
    bf16x8 ap = *(const bf16x8*)&Psm[(w * 16 + lr) * PSTR + ks * 32 + lg * 8];
    #pragma unroll
    for (int nn = 0; nn < 2; ++nn) {
      bf16x8 bv = *(const bf16x8*)&Vsm[(nn * 16 + lr) * PSTR + ks * 32 + lg * 8];
      oacc[nn] = __builtin_amdgcn_mfma_f32_16x16x32_bf16(ap, bv, oacc[nn], 0, 0, 0);
    }
  }

  float inv4[4];
  #pragma unroll
  for (int r = 0; r < 4; ++r) inv4[r] = Ls[w * 16 + lg * 4 + r];

  __syncthreads();   // all PV reads of V done before Osm overlays it
  #pragma unroll
  for (int nn = 0; nn < 2; ++nn)
    #pragma unroll
    for (int r = 0; r < 4; ++r)
      Osm[(w * 16 + lg * 4 + r) * 36 + nn * 16 + lr] = oacc[nn][r] * inv4[r];
  __syncthreads();
  {
    const int q = t >> 2, dq = (t & 3) * 8;
    const int qy = (p / NWIN) * 8 + (q >> 3);
    const int qx = (p % NWIN) * 8 + (q & 7);
    float vo[8];
    #pragma unroll
    for (int e = 0; e < 8; ++e) vo[e] = Osm[q * 36 + dq + e];
    ushort4 o0 = { f2bf(vo[0]), f2bf(vo[1]), f2bf(vo[2]), f2bf(vo[3]) };
    ushort4 o1 = { f2bf(vo[4]), f2bf(vo[5]), f2bf(vo[6]), f2bf(vo[7]) };
    unsigned short* op = &o_bf[((size_t)((n * HWDIM + qy) * HWDIM + qx)) * 256 + h * 32 + dq];
    *(ushort4*)op = o0;
    *(ushort4*)&op[4] = o1;
  }
}

// ---------------------------------------------------------------------------
// LEPE: thread = (pixel, 8-ch group). 3136 blocks. fp32 accum, bf16 RMW.
// ---------------------------------------------------------------------------
__global__ __launch_bounds__(256) void lepe_add(
    const unsigned short* __restrict__ v_bf, const float* __restrict__ Wc,
    const float* __restrict__ bias, unsigned short* __restrict__ o_bf)
{
  const int gid = blockIdx.x * 256 + threadIdx.x;
  const int c8 = (gid & 31) * 8;
  const int pix = gid >> 5;
  const int n = pix / (HWDIM * HWDIM);
  const int rem = pix - n * (HWDIM * HWDIM);
  const int y = rem / HWDIM, x = rem - y * HWDIM;

  float acc[8];
  {
    float4 b0 = *(const float4*)&bias[c8];
    float4 b1 = *(const float4*)&bias[c8 + 4];
    acc[0]=b0.x; acc[1]=b0.y; acc[2]=b0.z; acc[3]=b0.w;
    acc[4]=b1.x; acc[5]=b1.y; acc[6]=b1.z; acc[7]=b1.w;
  }

  #pragma unroll
  for (int ky = 0; ky < 5; ++ky) {
    const int sy = y + ky - 2;
    if (sy < 0 || sy >= HWDIM) continue;
    #pragma unroll
    for (int kx = 0; kx < 5; ++kx) {
      const int sx = x + kx - 2;
      if (sx < 0 || sx >= HWDIM) continue;
      const bf16x8 vv = *(const bf16x8*)&v_bf[((size_t)((n * HWDIM + sy) * HWDIM + sx)) * 256 + c8];
      const float* wp = &Wc[(ky * 5 + kx) * 256 + c8];
      float4 w0 = *(const float4*)wp;
      float4 w1 = *(const float4*)(wp + 4);
      acc[0] = fmaf(w0.x, bf2f((unsigned short)vv[0]), acc[0]);
      acc[1] = fmaf(w0.y, bf2f((unsigned short)vv[1]), acc[1]);
      acc[2] = fmaf(w0.z, bf2f((unsigned short)vv[2]), acc[2]);
      acc[3] = fmaf(w0.w, bf2f((unsigned short)vv[3]), acc[3]);
      acc[4] = fmaf(w1.x, bf2f((unsigned short)vv[4]), acc[4]);
      acc[5] = fmaf(w1.y, bf2f((unsigned short)vv[5]), acc[5]);
      acc[6] = fmaf(w1.z, bf2f((unsigned short)vv[6]), acc[6]);
      acc[7] = fmaf(w1.w, bf2f((unsigned short)vv[7]), acc[7]);
    }
  }

  unsigned short* op = &o_bf[(size_t)pix * 256 + c8];
  const bf16x8 ov = *(const bf16x8*)op;
  ushort4 o0 = { f2bf(bf2f((unsigned short)ov[0]) + acc[0]),
                 f2bf(bf2f((unsigned short)ov[1]) + acc[1]),
                 f2bf(bf2f((unsigned short)ov[2]) + acc[2]),
                 f2bf(bf2f((unsigned short)ov[3]) + acc[3]) };
  ushort4 o1 = { f2bf(bf2f((unsigned short)ov[4]) + acc[4]),
                 f2bf(bf2f((unsigned short)ov[5]) + acc[5]),
                 f2bf(bf2f((unsigned short)ov[6]) + acc[6]),
                 f2bf(bf2f((unsigned short)ov[7]) + acc[7]) };
  *(ushort4*)op = o0;
  *(ushort4*)(op + 4) = o1;
}

// ---------------------------------------------------------------------------
extern "C" void kernel_launch(void* const* d_in, const int* in_sizes, int n_in,
                              void* d_out, int out_size, void* d_ws, size_t ws_size,
                              hipStream_t stream)
{
  const float* x      = (const float*)d_in[0];
  const float* W_qkv  = (const float*)d_in[1];
  const float* b_qkv  = (const float*)d_in[2];
  const float* lepe_w = (const float*)d_in[3];
  const float* lepe_b = (const float*)d_in[4];
  const float* W_o    = (const float*)d_in[5];
  const float* b_o    = (const float*)d_in[6];
  float* out = (float*)d_out;

  char* ws = (char*)d_ws;
  const size_t IMG = (size_t)NPIX * 256;          // elems per image buffer
  unsigned short* x_bf    = (unsigned short*)(ws);
  unsigned short* q_bf    = (unsigned short*)(ws + 2*IMG);
  unsigned short* k_bf    = (unsigned short*)(ws + 4*IMG);
  unsigned short* v_bf    = (unsigned short*)(ws + 6*IMG);
  unsigned short* attn_bf = (unsigned short*)(ws + 8*IMG);
  unsigned short* Wt_qkv  = (unsigned short*)(ws + 10*IMG);
  unsigned short* Wt_o    = (unsigned short*)(ws + 10*IMG + 393216);
  float*          b_s     = (float*)         (ws + 10*IMG + 393216 + 131072);
  float*          x_win   = (float*)         (ws + 10*IMG + 393216 + 131072 + 4096);
  float*          q_win   = x_win + (size_t)NBATCH * P2 * 256;
  float*          k_win   = q_win + (size_t)NBATCH * P2 * 256;
  int*            ridx    = (int*)(k_win + (size_t)NBATCH * P2 * 256);
  float*          Wc      = (float*)(ridx + (size_t)NBATCH * P2 * TOPK);

  conv_xwin<<<NBATCH * P2, 256, 0, stream>>>(x, x_bf, x_win);
  prep_w<<<1052, 256, 0, stream>>>(W_qkv, b_qkv, W_o, lepe_w, Wt_qkv, Wt_o, b_s, Wc);
  win_gemm<<<NBATCH * P2, 256, 0, stream>>>(x_win, W_qkv, b_qkv, q_win, k_win);
  routing_topk<<<NBATCH * P2, 256, 0, stream>>>(q_win, k_win, ridx);
  gemm_mfma<0><<<dim3(196, 3), 512, 0, stream>>>(x_bf, Wt_qkv, b_s,
                                                 q_bf, k_bf, v_bf, nullptr);
  attn_mfma<<<NBATCH * P2 * HEADS, 256, 0, stream>>>(q_bf, k_bf, v_bf, ridx, attn_bf);
  lepe_add<<<3136, 256, 0, stream>>>(v_bf, Wc, lepe_b, attn_bf);
  gemm_mfma<1><<<dim3(196, 1), 512, 0, stream>>>(attn_bf, Wt_o, b_o,
                                                 nullptr, nullptr, nullptr, out);
}

// Round 7
// 213.623 us; speedup vs baseline: 2.8044x; 1.0178x over previous
//
#include <hip/hip_runtime.h>
#include <hip/hip_bf16.h>
#include <math.h>

#define NBATCH 8
#define HWDIM  56
#define NWIN   7
#define P2     49
#define HEADS  8
#define TOPK   4
#define SCALE  0.0625f
#define NPIX   (NBATCH*HWDIM*HWDIM)   // 25088

typedef __attribute__((ext_vector_type(8))) short bf16x8;
typedef __attribute__((ext_vector_type(4))) float f32x4;

#define GLOBAL_AS __attribute__((address_space(1)))
#define LDS_AS    __attribute__((address_space(3)))

__device__ __forceinline__ void gload16(const unsigned short* g, unsigned short* l) {
  __builtin_amdgcn_global_load_lds((const GLOBAL_AS unsigned int*)g,
                                   (LDS_AS unsigned int*)l, 16, 0, 0);
}

__device__ __forceinline__ unsigned short f2bf(float f) {
  __hip_bfloat16 h = __float2bfloat16(f);
  return *reinterpret_cast<unsigned short*>(&h);
}
__device__ __forceinline__ float bf2f(unsigned short h) {
  return __uint_as_float(((unsigned)h) << 16);
}

// ---------------------------------------------------------------------------
// fused_pre: blocks [0,392): per-window x->bf16 convert + window mean (LDS)
//            + fp32 q_win/k_win GEMV (exact routing path).
//            blocks [392,1444): weight prep (transpose->bf16, lepe w->[tap][c]).
// ---------------------------------------------------------------------------
__global__ __launch_bounds__(256) void fused_pre(
    const float* __restrict__ x, const float* __restrict__ W_qkv,
    const float* __restrict__ b_qkv, const float* __restrict__ W_o,
    const float* __restrict__ lepe_w,
    unsigned short* __restrict__ xb, float* __restrict__ q_win,
    float* __restrict__ k_win, unsigned short* __restrict__ Wt_qkv,
    unsigned short* __restrict__ Wt_o, float* __restrict__ b_s,
    float* __restrict__ Wc)
{
  __shared__ float4 red[256];
  __shared__ float xs[256];
  const int bidx = blockIdx.x;
  const int t = threadIdx.x;

  if (bidx < NBATCH * P2) {
    const int n = bidx / P2, p = bidx - n * P2;
    const int y0 = (p / NWIN) * 8, x0 = (p % NWIN) * 8;
    const int c4 = t & 63, pg = t >> 6;
    float4 s = {0.f, 0.f, 0.f, 0.f};
    #pragma unroll
    for (int k = 0; k < 16; ++k) {
      const int pix = pg * 16 + k;
      const int yy = y0 + (pix >> 3), xx = x0 + (pix & 7);
      const size_t off = ((size_t)((n * HWDIM + yy) * HWDIM + xx)) * 256 + c4 * 4;
      float4 v = *(const float4*)&x[off];
      ushort4 o = { f2bf(v.x), f2bf(v.y), f2bf(v.z), f2bf(v.w) };
      *(ushort4*)&xb[off] = o;
      s.x += v.x; s.y += v.y; s.z += v.z; s.w += v.w;
    }
    red[t] = s;
    __syncthreads();
    if (pg == 0) {
      float4 a = red[c4], b = red[64 + c4], c = red[128 + c4], d = red[192 + c4];
      float4 o = { (a.x + b.x + c.x + d.x) * (1.f/64.f),
                   (a.y + b.y + c.y + d.y) * (1.f/64.f),
                   (a.z + b.z + c.z + d.z) * (1.f/64.f),
                   (a.w + b.w + c.w + d.w) * (1.f/64.f) };
      *(float4*)&xs[c4 * 4] = o;
    }
    __syncthreads();
    float aq = 0.f, ak = 0.f;
    for (int cc = 0; cc < 256; ++cc) {
      const float xv = xs[cc];
      aq = fmaf(xv, W_qkv[cc * 768 + t], aq);
      ak = fmaf(xv, W_qkv[cc * 768 + 256 + t], ak);
    }
    q_win[(size_t)bidx * 256 + t] = aq + b_qkv[t];
    k_win[(size_t)bidx * 256 + t] = ak + b_qkv[256 + t];
  } else {
    const int idx = (bidx - NBATCH * P2) * 256 + t;
    if (idx < 768 * 256) {
      const int nn = idx >> 8, cc = idx & 255;
      float v = W_qkv[cc * 768 + nn];
      if (nn < 256) v *= SCALE;
      Wt_qkv[idx] = f2bf(v);
    } else if (idx < 768 * 256 + 256 * 256) {
      const int j = idx - 768 * 256;
      const int nn = j >> 8, cc = j & 255;
      Wt_o[j] = f2bf(W_o[cc * 256 + nn]);
    } else if (idx < 768 * 256 + 256 * 256 + 768) {
      const int j = idx - (768 * 256 + 256 * 256);
      b_s[j] = b_qkv[j] * (j < 256 ? SCALE : 1.f);
    } else if (idx < 768 * 256 + 256 * 256 + 768 + 25 * 256) {
      const int j = idx - (768 * 256 + 256 * 256 + 768);
      const int tap = j >> 8, cc = j & 255;
      Wc[j] = lepe_w[cc * 25 + tap];
    }
  }
}

// ---------------------------------------------------------------------------
// Routing: grid = N*P2 blocks; 4 lanes x 64ch partials per logit;
// top-4 scan of 49 by lane 0 (fp32 exact).
// ---------------------------------------------------------------------------
__global__ __launch_bounds__(256) void routing_topk(
    const float* __restrict__ q_win, const float* __restrict__ k_win,
    int* __restrict__ r_idx)
{
  __shared__ float qs[256];
  __shared__ float logit[64];
  const int bidx = blockIdx.x;
  const int n = bidx / P2;
  const int t = threadIdx.x;
  qs[t] = q_win[(size_t)bidx * 256 + t];
  __syncthreads();
  const int qq = t >> 2, qt = t & 3;
  if (qq < P2) {
    const float* kb = k_win + ((size_t)(n * P2 + qq)) * 256 + qt * 64;
    float a = 0.f;
    #pragma unroll 8
    for (int i = 0; i < 64; ++i) a = fmaf(qs[qt * 64 + i], kb[i], a);
    a += __shfl_xor(a, 1);
    a += __shfl_xor(a, 2);
    if (qt == 0) logit[qq] = a;
  }
  __syncthreads();
  if (t == 0) {
    float bv0 = -3e38f, bv1 = -3e38f, bv2 = -3e38f, bv3 = -3e38f;
    int bi0 = 0, bi1 = 0, bi2 = 0, bi3 = 0;
    for (int q2 = 0; q2 < P2; ++q2) {
      const float v = logit[q2];
      if (v > bv0) { bv3=bv2; bi3=bi2; bv2=bv1; bi2=bi1; bv1=bv0; bi1=bi0; bv0=v; bi0=q2; }
      else if (v > bv1) { bv3=bv2; bi3=bi2; bv2=bv1; bi2=bi1; bv1=v; bi1=q2; }
      else if (v > bv2) { bv3=bv2; bi3=bi2; bv2=v; bi2=q2; }
      else if (v > bv3) { bv3=v; bi3=q2; }
    }
    int* rp = r_idx + (size_t)bidx * TOPK;
    rp[0] = bi0; rp[1] = bi1; rp[2] = bi2; rp[3] = bi3;
  }
}

// ---------------------------------------------------------------------------
// bf16 MFMA GEMM: 128x256 tile, BK=64, 512 threads / 8 waves (2x4),
// global_load_lds staging (linear LDS, source-side XOR swizzle).
// MODE 0: bf16 out -> C0/C1/C2 selected by bn (QKV). MODE 1: fp32 out Cf.
// ---------------------------------------------------------------------------
template<int MODE>
__global__ __launch_bounds__(512) void gemm_mfma(
    const unsigned short* __restrict__ A,
    const unsigned short* __restrict__ Bt,
    const float* __restrict__ bias,
    unsigned short* __restrict__ C0, unsigned short* __restrict__ C1,
    unsigned short* __restrict__ C2, float* __restrict__ Cf)
{
  __shared__ char smem[49152];
  unsigned short* Asm = (unsigned short*)smem;            // [128][64] bf16, chunk-XOR
  unsigned short* Bsm = (unsigned short*)(smem + 16384);  // [256][64] bf16, chunk-XOR
  float* Cs = (float*)smem;                               // [32][256] f32 (reuse)

  const int t = threadIdx.x;
  const int w = t >> 6, l = t & 63;
  const int wr = w >> 2, wc = w & 3;              // 2 x 4 wave grid
  const int lr = l & 15, lg = l >> 4;
  const int bm = blockIdx.x, bn = blockIdx.y;
  const int row0 = bm * 128, col0 = bn * 256;

  const f32x4 fzero = {0.f, 0.f, 0.f, 0.f};
  f32x4 acc[4][4];
  #pragma unroll
  for (int m = 0; m < 4; ++m)
    #pragma unroll
    for (int n = 0; n < 4; ++n) acc[m][n] = fzero;

  const int srow  = t >> 3;                        // 0..63
  const int skoff = ((t & 7) ^ (srow & 7)) * 8;    // pre-swizzled global k offset

  for (int step = 0; step < 4; ++step) {
    const int k0 = step * 64;
    #pragma unroll
    for (int i = 0; i < 2; ++i)
      gload16(&A [(size_t)(row0 + i*64 + srow) * 256 + k0 + skoff],
              Asm + i*4096 + t*8);
    #pragma unroll
    for (int i = 0; i < 4; ++i)
      gload16(&Bt[(size_t)(col0 + i*64 + srow) * 256 + k0 + skoff],
              Bsm + i*4096 + t*8);
    __syncthreads();   // drains vmcnt -> tiles ready
    __builtin_amdgcn_s_setprio(1);
    #pragma unroll
    for (int kk = 0; kk < 2; ++kk) {
      bf16x8 af[4], bb[4];
      #pragma unroll
      for (int m = 0; m < 4; ++m)
        af[m] = *(const bf16x8*)&Asm[(wr*64 + m*16 + lr) * 64 + ((kk*4 + lg) ^ (lr & 7)) * 8];
      #pragma unroll
      for (int n = 0; n < 4; ++n)
        bb[n] = *(const bf16x8*)&Bsm[(wc*64 + n*16 + lr) * 64 + ((kk*4 + lg) ^ (lr & 7)) * 8];
      #pragma unroll
      for (int m = 0; m < 4; ++m)
        #pragma unroll
        for (int n = 0; n < 4; ++n)
          acc[m][n] = __builtin_amdgcn_mfma_f32_16x16x32_bf16(af[m], bb[n], acc[m][n], 0, 0, 0);
    }
    __builtin_amdgcn_s_setprio(0);
    __syncthreads();   // protect LDS before next-step staging overwrites
  }

  float bcol[4];
  #pragma unroll
  for (int n = 0; n < 4; ++n) bcol[n] = bias[col0 + wc*64 + n*16 + lr];

  #pragma unroll
  for (int hf = 0; hf < 4; ++hf) {
    if (hf) __syncthreads();
    if (wr == (hf >> 1)) {
      const int mbase = (hf & 1) * 2;
      #pragma unroll
      for (int mm = 0; mm < 2; ++mm)
        #pragma unroll
        for (int n = 0; n < 4; ++n)
          #pragma unroll
          for (int r = 0; r < 4; ++r) {
            const int lrow = mm*16 + lg*4 + r;          // 0..31 (quarter-local)
            const int col  = wc*64 + n*16 + lr;         // 0..255
            const int csw  = col ^ ((lrow & 7) << 2);
            Cs[lrow * 256 + csw] = acc[mbase + mm][n][r] + bcol[n];
          }
    }
    __syncthreads();
    #pragma unroll
    for (int it = 0; it < 4; ++it) {
      const int d = (it * 512 + t) * 4;
      const int lrow = d >> 8;
      const int colL = (d & 255) ^ ((lrow & 7) << 2);
      f32x4 v = *(const f32x4*)&Cs[d];
      const size_t grow = (size_t)(row0 + hf*32 + lrow);
      if (MODE == 0) {
        unsigned short* Cp = (bn == 0) ? C0 : (bn == 1) ? C1 : C2;
        ushort4 o = { f2bf(v[0]), f2bf(v[1]), f2bf(v[2]), f2bf(v[3]) };
        *(ushort4*)&Cp[grow * 256 + colL] = o;
      } else {
        float4 o = { v[0], v[1], v[2], v[3] };
        *(float4*)&Cf[grow * 256 + colL] = o;
      }
    }
  }
}

// ---------------------------------------------------------------------------
// MFMA gathered attention + fused LEPE. grid = N*P2*HEADS, 256 thr / 4 waves.
// Swapped QK^T -> per-lane softmax -> packed P -> PV -> (attn + lepe) store.
// Each block adds the 5x5 depthwise conv for its own 64 pixels x 32 channels.
// ---------------------------------------------------------------------------
#define PSTR 272     // P / V^T row stride in elems (544 B)

__global__ __launch_bounds__(256) void attn_mfma(
    const unsigned short* __restrict__ q_bf,
    const unsigned short* __restrict__ k_bf,
    const unsigned short* __restrict__ v_bf,
    const int* __restrict__ r_idx,
    const float* __restrict__ Wc,        // [25][256] lepe weights
    const float* __restrict__ lepe_b,    // [256]
    unsigned short* __restrict__ o_bf)
{
  __shared__ char smem[52480];
  unsigned short* Ksm = (unsigned short*)smem;              // [256][32] bf16
  unsigned short* Qsm = (unsigned short*)(smem + 16384);    // [64][32] bf16
  unsigned short* Psm = (unsigned short*)smem;              // [64][PSTR] (overlays K,Q)
  unsigned short* Vsm = (unsigned short*)(smem + 34816);    // [32][PSTR] (V^T)
  float*          Osm = (float*)(smem + 34816);             // [64][36] f32 (overlays V)
  float*          Ls  = (float*)(smem + 52224);             // [64] inv-sum

  const int b = blockIdx.x;
  const int h = b & 7;
  const int np = b >> 3;
  const int n = np / P2, p = np - n * P2;
  const int t = threadIdx.x;
  const int w = t >> 6, l = t & 63;
  const int lr = l & 15, lg = l >> 4;

  const int4 rv = *(const int4*)&r_idx[np * 4];

  // ---- stage K + Q via global_load_lds ----
  {
    const int pix = t >> 2, ch = t & 3;
    #pragma unroll
    for (int i = 0; i < 4; ++i) {
      const int wv = (&rv.x)[i];
      const int ky = (wv / NWIN) * 8 + (pix >> 3);
      const int kx = (wv % NWIN) * 8 + (pix & 7);
      const size_t goff = ((size_t)((n * HWDIM + ky) * HWDIM + kx)) * 256 + h * 32;
      gload16(&k_bf[goff + ch * 8], Ksm + i * 2048 + t * 8);
    }
    const int qy = (p / NWIN) * 8 + (pix >> 3);
    const int qx = (p % NWIN) * 8 + (pix & 7);
    gload16(&q_bf[((size_t)((n * HWDIM + qy) * HWDIM + qx)) * 256 + h * 32 + ch * 8],
            Qsm + t * 8);
  }
  // ---- stage V^T (scalar transpose writes, col = key index t) ----
  {
    const int s = t >> 6, pix = t & 63;
    const int wv = (&rv.x)[s];
    const int ky = (wv / NWIN) * 8 + (pix >> 3);
    const int kx = (wv % NWIN) * 8 + (pix & 7);
    const size_t goff = ((size_t)((n * HWDIM + ky) * HWDIM + kx)) * 256 + h * 32;
    #pragma unroll
    for (int j = 0; j < 4; ++j) {
      bf16x8 vv = *(const bf16x8*)&v_bf[goff + j * 8];
      #pragma unroll
      for (int e = 0; e < 8; ++e)
        Vsm[(j * 8 + e) * PSTR + t] = (unsigned short)vv[e];
    }
  }
  __syncthreads();

  // ---- swapped QK^T: sf[f] = S^T[key block f][q = w*16+lr] ----
  f32x4 sf[16];
  {
    const f32x4 fzero = {0.f, 0.f, 0.f, 0.f};
    bf16x8 aq = *(const bf16x8*)&Qsm[(w * 16 + lr) * 32 + lg * 8];
    __builtin_amdgcn_s_setprio(1);
    #pragma unroll
    for (int f = 0; f < 16; ++f) {
      bf16x8 bk = *(const bf16x8*)&Ksm[(f * 16 + lr) * 32 + lg * 8];
      sf[f] = __builtin_amdgcn_mfma_f32_16x16x32_bf16(bk, aq, fzero, 0, 0, 0);
    }
    __builtin_amdgcn_s_setprio(0);
  }

  // ---- per-lane softmax over 64 in-lane keys + lg-combine (xor 16,32) ----
  {
    float mx = sf[0][0];
    #pragma unroll
    for (int f = 0; f < 16; ++f)
      #pragma unroll
      for (int r = 0; r < 4; ++r) mx = fmaxf(mx, sf[f][r]);
    mx = fmaxf(mx, __shfl_xor(mx, 16));
    mx = fmaxf(mx, __shfl_xor(mx, 32));
    float sum = 0.f;
    #pragma unroll
    for (int f = 0; f < 16; ++f)
      #pragma unroll
      for (int r = 0; r < 4; ++r) {
        float e = __expf(sf[f][r] - mx);
        sf[f][r] = e; sum += e;
      }
    sum += __shfl_xor(sum, 16);
    sum += __shfl_xor(sum, 32);
    if (lg == 0) Ls[w * 16 + lr] = 1.f / sum;
  }
  __syncthreads();   // all QK^T reads of K/Q done before P overlays them

  // ---- P write: unnormalized exp, 4 consecutive keys per b64 ----
  #pragma unroll
  for (int f = 0; f < 16; ++f) {
    ushort4 pk = { f2bf(sf[f][0]), f2bf(sf[f][1]), f2bf(sf[f][2]), f2bf(sf[f][3]) };
    *(ushort4*)&Psm[(w * 16 + lr) * PSTR + f * 16 + lg * 4] = pk;
  }

  // ---- PV: out[q][d] = P[q][:] . V[:, d]  (P self-wave, no barrier) ----
  f32x4 oacc[2];
  oacc[0] = (f32x4){0.f, 0.f, 0.f, 0.f};
  oacc[1] = (f32x4){0.f, 0.f, 0.f, 0.f};
  __builtin_amdgcn_s_setprio(1);
  #pragma unroll
  for (int ks = 0; ks < 8; ++ks) {
    bf16x8 ap = *(const bf16x8*)&Psm[(w * 16 + lr) * PSTR + ks * 32 + lg * 8];
    #pragma unroll
    for (int nn = 0; nn < 2; ++nn) {
      bf16x8 bv = *(const bf16x8*)&Vsm[(nn * 16 + lr) * PSTR + ks * 32 + lg * 8];
      oacc[nn] = __builtin_amdgcn_mfma_f32_16x16x32_bf16(ap, bv, oacc[nn], 0, 0, 0);
    }
  }
  __builtin_amdgcn_s_setprio(0);

  float inv4[4];
  #pragma unroll
  for (int r = 0; r < 4; ++r) inv4[r] = Ls[w * 16 + lg * 4 + r];

  __syncthreads();   // all PV reads of V done before Osm overlays it
  #pragma unroll
  for (int nn = 0; nn < 2; ++nn)
    #pragma unroll
    for (int r = 0; r < 4; ++r)
      Osm[(w * 16 + lg * 4 + r) * 36 + nn * 16 + lr] = oacc[nn][r] * inv4[r];
  __syncthreads();

  // ---- fused LEPE + store: thread owns (pixel q, 8 channels c0..c0+7) ----
  {
    const int q = t >> 2, dq = (t & 3) * 8;
    const int qy = (p / NWIN) * 8 + (q >> 3);
    const int qx = (p % NWIN) * 8 + (q & 7);
    const int c0 = h * 32 + dq;

    float acc[8];
    {
      float4 b0 = *(const float4*)&lepe_b[c0];
      float4 b1 = *(const float4*)&lepe_b[c0 + 4];
      acc[0]=b0.x; acc[1]=b0.y; acc[2]=b0.z; acc[3]=b0.w;
      acc[4]=b1.x; acc[5]=b1.y; acc[6]=b1.z; acc[7]=b1.w;
    }
    #pragma unroll
    for (int ky = 0; ky < 5; ++ky) {
      const int sy = qy + ky - 2;
      if (sy < 0 || sy >= HWDIM) continue;
      #pragma unroll
      for (int kx = 0; kx < 5; ++kx) {
        const int sx = qx + kx - 2;
        if (sx < 0 || sx >= HWDIM) continue;
        const bf16x8 vv = *(const bf16x8*)&v_bf[((size_t)((n * HWDIM + sy) * HWDIM + sx)) * 256 + c0];
        const float* wp = &Wc[(ky * 5 + kx) * 256 + c0];
        float4 w0 = *(const float4*)wp;
        float4 w1 = *(const float4*)(wp + 4);
        acc[0] = fmaf(w0.x, bf2f((unsigned short)vv[0]), acc[0]);
        acc[1] = fmaf(w0.y, bf2f((unsigned short)vv[1]), acc[1]);
        acc[2] = fmaf(w0.z, bf2f((unsigned short)vv[2]), acc[2]);
        acc[3] = fmaf(w0.w, bf2f((unsigned short)vv[3]), acc[3]);
        acc[4] = fmaf(w1.x, bf2f((unsigned short)vv[4]), acc[4]);
        acc[5] = fmaf(w1.y, bf2f((unsigned short)vv[5]), acc[5]);
        acc[6] = fmaf(w1.z, bf2f((unsigned short)vv[6]), acc[6]);
        acc[7] = fmaf(w1.w, bf2f((unsigned short)vv[7]), acc[7]);
      }
    }
    float vo[8];
    #pragma unroll
    for (int e = 0; e < 8; ++e) vo[e] = Osm[q * 36 + dq + e] + acc[e];
    ushort4 o0 = { f2bf(vo[0]), f2bf(vo[1]), f2bf(vo[2]), f2bf(vo[3]) };
    ushort4 o1 = { f2bf(vo[4]), f2bf(vo[5]), f2bf(vo[6]), f2bf(vo[7]) };
    unsigned short* op = &o_bf[((size_t)((n * HWDIM + qy) * HWDIM + qx)) * 256 + c0];
    *(ushort4*)op = o0;
    *(ushort4*)&op[4] = o1;
  }
}

// ---------------------------------------------------------------------------
extern "C" void kernel_launch(void* const* d_in, const int* in_sizes, int n_in,
                              void* d_out, int out_size, void* d_ws, size_t ws_size,
                              hipStream_t stream)
{
  const float* x      = (const float*)d_in[0];
  const float* W_qkv  = (const float*)d_in[1];
  const float* b_qkv  = (const float*)d_in[2];
  const float* lepe_w = (const float*)d_in[3];
  const float* lepe_b = (const float*)d_in[4];
  const float* W_o    = (const float*)d_in[5];
  const float* b_o    = (const float*)d_in[6];
  float* out = (float*)d_out;

  char* ws = (char*)d_ws;
  const size_t IMG = (size_t)NPIX * 256;          // elems per image buffer
  unsigned short* x_bf    = (unsigned short*)(ws);
  unsigned short* q_bf    = (unsigned short*)(ws + 2*IMG);
  unsigned short* k_bf    = (unsigned short*)(ws + 4*IMG);
  unsigned short* v_bf    = (unsigned short*)(ws + 6*IMG);
  unsigned short* attn_bf = (unsigned short*)(ws + 8*IMG);
  unsigned short* Wt_qkv  = (unsigned short*)(ws + 10*IMG);
  unsigned short* Wt_o    = (unsigned short*)(ws + 10*IMG + 393216);
  float*          b_s     = (float*)         (ws + 10*IMG + 393216 + 131072);
  float*          q_win   = (float*)         (ws + 10*IMG + 393216 + 131072 + 4096);
  float*          k_win   = q_win + (size_t)NBATCH * P2 * 256;
  int*            ridx    = (int*)(k_win + (size_t)NBATCH * P2 * 256);
  float*          Wc      = (float*)(ridx + (size_t)NBATCH * P2 * TOPK);

  fused_pre<<<NBATCH * P2 + 1052, 256, 0, stream>>>(
      x, W_qkv, b_qkv, W_o, lepe_w, x_bf, q_win, k_win, Wt_qkv, Wt_o, b_s, Wc);
  routing_topk<<<NBATCH * P2, 256, 0, stream>>>(q_win, k_win, ridx);
  gemm_mfma<0><<<dim3(196, 3), 512, 0, stream>>>(x_bf, Wt_qkv, b_s,
                                                 q_bf, k_bf, v_bf, nullptr);
  attn_mfma<<<NBATCH * P2 * HEADS, 256, 0, stream>>>(q_bf, k_bf, v_bf, ridx,
                                                     Wc, lepe_b, attn_bf);
  gemm_mfma<1><<<dim3(196, 1), 512, 0, stream>>>(attn_bf, Wt_o, b_o,
                                                 nullptr, nullptr, nullptr, out);
}

// Round 8
// 212.949 us; speedup vs baseline: 2.8133x; 1.0032x over previous
//
#include <hip/hip_runtime.h>
#include <hip/hip_bf16.h>
#include <math.h>

#define NBATCH 8
#define HWDIM  56
#define NWIN   7
#define P2     49
#define HEADS  8
#define TOPK   4
#define SCALE  0.0625f
#define NPIX   (NBATCH*HWDIM*HWDIM)   // 25088

typedef __attribute__((ext_vector_type(8))) short bf16x8;
typedef __attribute__((ext_vector_type(4))) float f32x4;

#define GLOBAL_AS __attribute__((address_space(1)))
#define LDS_AS    __attribute__((address_space(3)))

__device__ __forceinline__ void gload16(const unsigned short* g, unsigned short* l) {
  __builtin_amdgcn_global_load_lds((const GLOBAL_AS unsigned int*)g,
                                   (LDS_AS unsigned int*)l, 16, 0, 0);
}

__device__ __forceinline__ unsigned short f2bf(float f) {
  __hip_bfloat16 h = __float2bfloat16(f);
  return *reinterpret_cast<unsigned short*>(&h);
}
__device__ __forceinline__ float bf2f(unsigned short h) {
  return __uint_as_float(((unsigned)h) << 16);
}

// ---------------------------------------------------------------------------
// fused_pre: blocks [0,392): per-window x->bf16 convert + window mean (LDS)
//            + fp32 q_win/k_win GEMV (exact routing path).
//            blocks [392,1444): weight prep (transpose->bf16, lepe w->[tap][c]).
// ---------------------------------------------------------------------------
__global__ __launch_bounds__(256) void fused_pre(
    const float* __restrict__ x, const float* __restrict__ W_qkv,
    const float* __restrict__ b_qkv, const float* __restrict__ W_o,
    const float* __restrict__ lepe_w,
    unsigned short* __restrict__ xb, float* __restrict__ q_win,
    float* __restrict__ k_win, unsigned short* __restrict__ Wt_qkv,
    unsigned short* __restrict__ Wt_o, float* __restrict__ b_s,
    float* __restrict__ Wc)
{
  __shared__ float4 red[256];
  __shared__ float xs[256];
  const int bidx = blockIdx.x;
  const int t = threadIdx.x;

  if (bidx < NBATCH * P2) {
    const int n = bidx / P2, p = bidx - n * P2;
    const int y0 = (p / NWIN) * 8, x0 = (p % NWIN) * 8;
    const int c4 = t & 63, pg = t >> 6;
    float4 s = {0.f, 0.f, 0.f, 0.f};
    #pragma unroll
    for (int k = 0; k < 16; ++k) {
      const int pix = pg * 16 + k;
      const int yy = y0 + (pix >> 3), xx = x0 + (pix & 7);
      const size_t off = ((size_t)((n * HWDIM + yy) * HWDIM + xx)) * 256 + c4 * 4;
      float4 v = *(const float4*)&x[off];
      ushort4 o = { f2bf(v.x), f2bf(v.y), f2bf(v.z), f2bf(v.w) };
      *(ushort4*)&xb[off] = o;
      s.x += v.x; s.y += v.y; s.z += v.z; s.w += v.w;
    }
    red[t] = s;
    __syncthreads();
    if (pg == 0) {
      float4 a = red[c4], b = red[64 + c4], c = red[128 + c4], d = red[192 + c4];
      float4 o = { (a.x + b.x + c.x + d.x) * (1.f/64.f),
                   (a.y + b.y + c.y + d.y) * (1.f/64.f),
                   (a.z + b.z + c.z + d.z) * (1.f/64.f),
                   (a.w + b.w + c.w + d.w) * (1.f/64.f) };
      *(float4*)&xs[c4 * 4] = o;
    }
    __syncthreads();
    float aq = 0.f, ak = 0.f;
    for (int cc = 0; cc < 256; ++cc) {
      const float xv = xs[cc];
      aq = fmaf(xv, W_qkv[cc * 768 + t], aq);
      ak = fmaf(xv, W_qkv[cc * 768 + 256 + t], ak);
    }
    q_win[(size_t)bidx * 256 + t] = aq + b_qkv[t];
    k_win[(size_t)bidx * 256 + t] = ak + b_qkv[256 + t];
  } else {
    const int idx = (bidx - NBATCH * P2) * 256 + t;
    if (idx < 768 * 256) {
      const int nn = idx >> 8, cc = idx & 255;
      float v = W_qkv[cc * 768 + nn];
      if (nn < 256) v *= SCALE;
      Wt_qkv[idx] = f2bf(v);
    } else if (idx < 768 * 256 + 256 * 256) {
      const int j = idx - 768 * 256;
      const int nn = j >> 8, cc = j & 255;
      Wt_o[j] = f2bf(W_o[cc * 256 + nn]);
    } else if (idx < 768 * 256 + 256 * 256 + 768) {
      const int j = idx - (768 * 256 + 256 * 256);
      b_s[j] = b_qkv[j] * (j < 256 ? SCALE : 1.f);
    } else if (idx < 768 * 256 + 256 * 256 + 768 + 25 * 256) {
      const int j = idx - (768 * 256 + 256 * 256 + 768);
      const int tap = j >> 8, cc = j & 255;
      Wc[j] = lepe_w[cc * 25 + tap];
    }
  }
}

// ---------------------------------------------------------------------------
// Routing: grid = N*P2 blocks; 4 lanes x 64ch partials per logit;
// top-4 scan of 49 by lane 0 (fp32 exact).
// ---------------------------------------------------------------------------
__global__ __launch_bounds__(256) void routing_topk(
    const float* __restrict__ q_win, const float* __restrict__ k_win,
    int* __restrict__ r_idx)
{
  __shared__ float qs[256];
  __shared__ float logit[64];
  const int bidx = blockIdx.x;
  const int n = bidx / P2;
  const int t = threadIdx.x;
  qs[t] = q_win[(size_t)bidx * 256 + t];
  __syncthreads();
  const int qq = t >> 2, qt = t & 3;
  if (qq < P2) {
    const float* kb = k_win + ((size_t)(n * P2 + qq)) * 256 + qt * 64;
    float a = 0.f;
    #pragma unroll 8
    for (int i = 0; i < 64; ++i) a = fmaf(qs[qt * 64 + i], kb[i], a);
    a += __shfl_xor(a, 1);
    a += __shfl_xor(a, 2);
    if (qt == 0) logit[qq] = a;
  }
  __syncthreads();
  if (t == 0) {
    float bv0 = -3e38f, bv1 = -3e38f, bv2 = -3e38f, bv3 = -3e38f;
    int bi0 = 0, bi1 = 0, bi2 = 0, bi3 = 0;
    for (int q2 = 0; q2 < P2; ++q2) {
      const float v = logit[q2];
      if (v > bv0) { bv3=bv2; bi3=bi2; bv2=bv1; bi2=bi1; bv1=bv0; bi1=bi0; bv0=v; bi0=q2; }
      else if (v > bv1) { bv3=bv2; bi3=bi2; bv2=bv1; bi2=bi1; bv1=v; bi1=q2; }
      else if (v > bv2) { bv3=bv2; bi3=bi2; bv2=v; bi2=q2; }
      else if (v > bv3) { bv3=v; bi3=q2; }
    }
    int* rp = r_idx + (size_t)bidx * TOPK;
    rp[0] = bi0; rp[1] = bi1; rp[2] = bi2; rp[3] = bi3;
  }
}

// ---------------------------------------------------------------------------
// bf16 MFMA GEMM: 128x256 tile, BK=64, 512 threads / 8 waves (2x4),
// global_load_lds staging (linear LDS, source-side XOR swizzle).
// MODE 0: bf16 out -> C0/C1/C2 selected by bn (QKV). MODE 1: fp32 out Cf.
// ---------------------------------------------------------------------------
template<int MODE>
__global__ __launch_bounds__(512) void gemm_mfma(
    const unsigned short* __restrict__ A,
    const unsigned short* __restrict__ Bt,
    const float* __restrict__ bias,
    unsigned short* __restrict__ C0, unsigned short* __restrict__ C1,
    unsigned short* __restrict__ C2, float* __restrict__ Cf)
{
  __shared__ char smem[49152];
  unsigned short* Asm = (unsigned short*)smem;            // [128][64] bf16, chunk-XOR
  unsigned short* Bsm = (unsigned short*)(smem + 16384);  // [256][64] bf16, chunk-XOR
  float* Cs = (float*)smem;                               // [32][256] f32 (reuse)

  const int t = threadIdx.x;
  const int w = t >> 6, l = t & 63;
  const int wr = w >> 2, wc = w & 3;              // 2 x 4 wave grid
  const int lr = l & 15, lg = l >> 4;
  const int bm = blockIdx.x, bn = blockIdx.y;
  const int row0 = bm * 128, col0 = bn * 256;

  const f32x4 fzero = {0.f, 0.f, 0.f, 0.f};
  f32x4 acc[4][4];
  #pragma unroll
  for (int m = 0; m < 4; ++m)
    #pragma unroll
    for (int n = 0; n < 4; ++n) acc[m][n] = fzero;

  const int srow  = t >> 3;                        // 0..63
  const int skoff = ((t & 7) ^ (srow & 7)) * 8;    // pre-swizzled global k offset

  for (int step = 0; step < 4; ++step) {
    const int k0 = step * 64;
    #pragma unroll
    for (int i = 0; i < 2; ++i)
      gload16(&A [(size_t)(row0 + i*64 + srow) * 256 + k0 + skoff],
              Asm + i*4096 + t*8);
    #pragma unroll
    for (int i = 0; i < 4; ++i)
      gload16(&Bt[(size_t)(col0 + i*64 + srow) * 256 + k0 + skoff],
              Bsm + i*4096 + t*8);
    __syncthreads();   // drains vmcnt -> tiles ready
    __builtin_amdgcn_s_setprio(1);
    #pragma unroll
    for (int kk = 0; kk < 2; ++kk) {
      bf16x8 af[4], bb[4];
      #pragma unroll
      for (int m = 0; m < 4; ++m)
        af[m] = *(const bf16x8*)&Asm[(wr*64 + m*16 + lr) * 64 + ((kk*4 + lg) ^ (lr & 7)) * 8];
      #pragma unroll
      for (int n = 0; n < 4; ++n)
        bb[n] = *(const bf16x8*)&Bsm[(wc*64 + n*16 + lr) * 64 + ((kk*4 + lg) ^ (lr & 7)) * 8];
      #pragma unroll
      for (int m = 0; m < 4; ++m)
        #pragma unroll
        for (int n = 0; n < 4; ++n)
          acc[m][n] = __builtin_amdgcn_mfma_f32_16x16x32_bf16(af[m], bb[n], acc[m][n], 0, 0, 0);
    }
    __builtin_amdgcn_s_setprio(0);
    __syncthreads();   // protect LDS before next-step staging overwrites
  }

  float bcol[4];
  #pragma unroll
  for (int n = 0; n < 4; ++n) bcol[n] = bias[col0 + wc*64 + n*16 + lr];

  #pragma unroll
  for (int hf = 0; hf < 4; ++hf) {
    if (hf) __syncthreads();
    if (wr == (hf >> 1)) {
      const int mbase = (hf & 1) * 2;
      #pragma unroll
      for (int mm = 0; mm < 2; ++mm)
        #pragma unroll
        for (int n = 0; n < 4; ++n)
          #pragma unroll
          for (int r = 0; r < 4; ++r) {
            const int lrow = mm*16 + lg*4 + r;          // 0..31 (quarter-local)
            const int col  = wc*64 + n*16 + lr;         // 0..255
            const int csw  = col ^ ((lrow & 7) << 2);
            Cs[lrow * 256 + csw] = acc[mbase + mm][n][r] + bcol[n];
          }
    }
    __syncthreads();
    #pragma unroll
    for (int it = 0; it < 4; ++it) {
      const int d = (it * 512 + t) * 4;
      const int lrow = d >> 8;
      const int colL = (d & 255) ^ ((lrow & 7) << 2);
      f32x4 v = *(const f32x4*)&Cs[d];
      const size_t grow = (size_t)(row0 + hf*32 + lrow);
      if (MODE == 0) {
        unsigned short* Cp = (bn == 0) ? C0 : (bn == 1) ? C1 : C2;
        ushort4 o = { f2bf(v[0]), f2bf(v[1]), f2bf(v[2]), f2bf(v[3]) };
        *(ushort4*)&Cp[grow * 256 + colL] = o;
      } else {
        float4 o = { v[0], v[1], v[2], v[3] };
        *(float4*)&Cf[grow * 256 + colL] = o;
      }
    }
  }
}

// ---------------------------------------------------------------------------
// MFMA gathered attention + halo-staged LEPE. grid = N*P2*HEADS, 256 thr.
// Early register loads of v-halo/weights ride out QK^T/softmax/PV latency;
// P and V^T use chunk-XOR swizzled [.][256] LDS (bank-uniform b128).
// LDS 49.4 KB -> 3 blocks/CU.
// ---------------------------------------------------------------------------
__global__ __launch_bounds__(256) void attn_mfma(
    const unsigned short* __restrict__ q_bf,
    const unsigned short* __restrict__ k_bf,
    const unsigned short* __restrict__ v_bf,
    const int* __restrict__ r_idx,
    const float* __restrict__ Wc,        // [25][256] lepe weights
    const float* __restrict__ lepe_b,    // [256]
    unsigned short* __restrict__ o_bf)
{
  __shared__ char smem[49408];
  unsigned short* Ksm = (unsigned short*)smem;              // [256][32] bf16
  unsigned short* Qsm = (unsigned short*)(smem + 16384);    // [64][32] bf16
  unsigned short* Psm = (unsigned short*)smem;              // [64][256] swz (overlays K,Q)
  unsigned short* Vsm = (unsigned short*)(smem + 32768);    // [32][256] swz (V^T)
  float*          Osm = (float*)(smem + 32768);             // [64][36] f32 (overlays V)
  unsigned short* Hsm = (unsigned short*)smem;              // [144][32] halo (overlays P)
  float*          Wsm = (float*)(smem + 9216);              // [25][32] lepe w slice
  float*          Lbs = (float*)(smem + 12416);             // [32] lepe bias slice
  float*          Ls  = (float*)(smem + 49152);             // [64] inv-sum

  const int b = blockIdx.x;
  const int h = b & 7;
  const int np = b >> 3;
  const int n = np / P2, p = np - n * P2;
  const int t = threadIdx.x;
  const int w = t >> 6, l = t & 63;
  const int lr = l & 15, lg = l >> 4;
  const int y0 = (p / NWIN) * 8, x0 = (p % NWIN) * 8;

  const int4 rv = *(const int4*)&r_idx[np * 4];

  // ---- stage K + Q via global_load_lds (direct DMA, linear dest) ----
  {
    const int pix = t >> 2, ch = t & 3;
    #pragma unroll
    for (int i = 0; i < 4; ++i) {
      const int wv = (&rv.x)[i];
      const int ky = (wv / NWIN) * 8 + (pix >> 3);
      const int kx = (wv % NWIN) * 8 + (pix & 7);
      const size_t goff = ((size_t)((n * HWDIM + ky) * HWDIM + kx)) * 256 + h * 32;
      gload16(&k_bf[goff + ch * 8], Ksm + i * 2048 + t * 8);
    }
    const int qy = y0 + (pix >> 3), qx = x0 + (pix & 7);
    gload16(&q_bf[((size_t)((n * HWDIM + qy) * HWDIM + qx)) * 256 + h * 32 + ch * 8],
            Qsm + t * 8);
  }

  // ---- early register loads: V rows, lepe halo, lepe weights/bias ----
  bf16x8 vreg[4];
  {
    const int s = t >> 6, pix = t & 63;
    const int wv = (&rv.x)[s];
    const int ky = (wv / NWIN) * 8 + (pix >> 3);
    const int kx = (wv % NWIN) * 8 + (pix & 7);
    const size_t goff = ((size_t)((n * HWDIM + ky) * HWDIM + kx)) * 256 + h * 32;
    #pragma unroll
    for (int j = 0; j < 4; ++j)
      vreg[j] = *(const bf16x8*)&v_bf[goff + j * 8];
  }
  bf16x8 hreg[3];
  {
    const bf16x8 hz = {0,0,0,0,0,0,0,0};
    #pragma unroll
    for (int i = 0; i < 3; ++i) {
      hreg[i] = hz;
      const int u = t + i * 256;
      if (u < 576) {
        const int pu = u >> 2, cu = u & 3;
        const int hy = pu / 12, hx = pu - hy * 12;
        const int gy = y0 - 2 + hy, gx = x0 - 2 + hx;
        if (gy >= 0 && gy < HWDIM && gx >= 0 && gx < HWDIM)
          hreg[i] = *(const bf16x8*)&v_bf[((size_t)((n * HWDIM + gy) * HWDIM + gx)) * 256 + h * 32 + cu * 8];
      }
    }
  }
  float4 wreg = {0.f, 0.f, 0.f, 0.f};
  float  breg = 0.f;
  if (t < 200) wreg = *(const float4*)&Wc[(t >> 3) * 256 + h * 32 + (t & 7) * 4];
  else if (t < 232) breg = lepe_b[h * 32 + (t - 200)];

  // ---- V^T into swizzled LDS: elem [d][key] at chunk (key>>3)^(d&7) ----
  {
    const int key = t;
    #pragma unroll
    for (int j = 0; j < 4; ++j)
      #pragma unroll
      for (int e = 0; e < 8; ++e) {
        const int d = j * 8 + e;
        Vsm[d * 256 + (((key >> 3) ^ (d & 7)) << 3) + (key & 7)] = (unsigned short)vreg[j][e];
      }
  }
  __syncthreads();

  // ---- swapped QK^T: sf[f][r] = S[key=f*16+lg*4+r][q=w*16+lr] ----
  f32x4 sf[16];
  {
    const f32x4 fzero = {0.f, 0.f, 0.f, 0.f};
    bf16x8 aq = *(const bf16x8*)&Qsm[(w * 16 + lr) * 32 + lg * 8];
    __builtin_amdgcn_s_setprio(1);
    #pragma unroll
    for (int f = 0; f < 16; ++f) {
      bf16x8 bk = *(const bf16x8*)&Ksm[(f * 16 + lr) * 32 + lg * 8];
      sf[f] = __builtin_amdgcn_mfma_f32_16x16x32_bf16(bk, aq, fzero, 0, 0, 0);
    }
    __builtin_amdgcn_s_setprio(0);
  }

  // ---- per-lane softmax over 64 in-lane keys + lg-combine (xor 16,32) ----
  {
    float mx = sf[0][0];
    #pragma unroll
    for (int f = 0; f < 16; ++f)
      #pragma unroll
      for (int r = 0; r < 4; ++r) mx = fmaxf(mx, sf[f][r]);
    mx = fmaxf(mx, __shfl_xor(mx, 16));
    mx = fmaxf(mx, __shfl_xor(mx, 32));
    float sum = 0.f;
    #pragma unroll
    for (int f = 0; f < 16; ++f)
      #pragma unroll
      for (int r = 0; r < 4; ++r) {
        float e = __expf(sf[f][r] - mx);
        sf[f][r] = e; sum += e;
      }
    sum += __shfl_xor(sum, 16);
    sum += __shfl_xor(sum, 32);
    if (lg == 0) Ls[w * 16 + lr] = 1.f / sum;
  }
  __syncthreads();   // all QK^T reads of K/Q done before P overlays them

  // ---- P write: row w*16+lr, keys f*16+lg*4..+3 -> swizzled chunk ----
  #pragma unroll
  for (int f = 0; f < 16; ++f) {
    ushort4 pk = { f2bf(sf[f][0]), f2bf(sf[f][1]), f2bf(sf[f][2]), f2bf(sf[f][3]) };
    const int chs = ((f * 2 + (lg >> 1)) ^ (lr & 7));
    *(ushort4*)&Psm[(w * 16 + lr) * 256 + chs * 8 + (lg & 1) * 4] = pk;
  }

  // ---- PV: out[q][d] = P[q][:] . V[:, d]  (P rows self-wave) ----
  f32x4 oacc[2];
  oacc[0] = (f32x4){0.f, 0.f, 0.f, 0.f};
  oacc[1] = (f32x4){0.f, 0.f, 0.f, 0.f};
  __builtin_amdgcn_s_setprio(1);
  #pragma unroll
  for (int ks = 0; ks < 8; ++ks) {
    const int cs = (((ks * 4 + lg) ^ (lr & 7))) << 3;
    bf16x8 ap = *(const bf16x8*)&Psm[(w * 16 + lr) * 256 + cs];
    #pragma unroll
    for (int nn = 0; nn < 2; ++nn) {
      bf16x8 bv = *(const bf16x8*)&Vsm[(nn * 16 + lr) * 256 + cs];
      oacc[nn] = __builtin_amdgcn_mfma_f32_16x16x32_bf16(ap, bv, oacc[nn], 0, 0, 0);
    }
  }
  __builtin_amdgcn_s_setprio(0);

  float inv4[4];
  #pragma unroll
  for (int r = 0; r < 4; ++r) inv4[r] = Ls[w * 16 + lg * 4 + r];

  __syncthreads();   // PV reads of P/V done; Osm overlays V, halo overlays P

  // ---- write O, halo, weights into LDS ----
  #pragma unroll
  for (int nn = 0; nn < 2; ++nn)
    #pragma unroll
    for (int r = 0; r < 4; ++r)
      Osm[(w * 16 + lg * 4 + r) * 36 + nn * 16 + lr] = oacc[nn][r] * inv4[r];
  #pragma unroll
  for (int i = 0; i < 3; ++i) {
    const int u = t + i * 256;
    if (u < 576)
      *(bf16x8*)&Hsm[(u >> 2) * 32 + (u & 3) * 8] = hreg[i];
  }
  if (t < 200) *(float4*)&Wsm[(t >> 3) * 32 + (t & 7) * 4] = wreg;
  else if (t < 232) Lbs[t - 200] = breg;
  __syncthreads();

  // ---- LEPE from LDS + output store: thread = (pixel q, 8 channels) ----
  {
    const int q = t >> 2, dq8 = t & 3;
    const int qy_l = q >> 3, qx_l = q & 7;
    const int c0 = h * 32 + dq8 * 8;

    float accv[8];
    {
      f32x4 b0 = *(const f32x4*)&Lbs[dq8 * 8];
      f32x4 b1 = *(const f32x4*)&Lbs[dq8 * 8 + 4];
      accv[0]=b0[0]; accv[1]=b0[1]; accv[2]=b0[2]; accv[3]=b0[3];
      accv[4]=b1[0]; accv[5]=b1[1]; accv[6]=b1[2]; accv[7]=b1[3];
    }
    #pragma unroll
    for (int ky = 0; ky < 5; ++ky)
      #pragma unroll
      for (int kx = 0; kx < 5; ++kx) {
        const int pix = (qy_l + ky) * 12 + (qx_l + kx);
        const bf16x8 hv = *(const bf16x8*)&Hsm[pix * 32 + dq8 * 8];
        const f32x4 w0 = *(const f32x4*)&Wsm[(ky * 5 + kx) * 32 + dq8 * 8];
        const f32x4 w1 = *(const f32x4*)&Wsm[(ky * 5 + kx) * 32 + dq8 * 8 + 4];
        accv[0] = fmaf(w0[0], bf2f((unsigned short)hv[0]), accv[0]);
        accv[1] = fmaf(w0[1], bf2f((unsigned short)hv[1]), accv[1]);
        accv[2] = fmaf(w0[2], bf2f((unsigned short)hv[2]), accv[2]);
        accv[3] = fmaf(w0[3], bf2f((unsigned short)hv[3]), accv[3]);
        accv[4] = fmaf(w1[0], bf2f((unsigned short)hv[4]), accv[4]);
        accv[5] = fmaf(w1[1], bf2f((unsigned short)hv[5]), accv[5]);
        accv[6] = fmaf(w1[2], bf2f((unsigned short)hv[6]), accv[6]);
        accv[7] = fmaf(w1[3], bf2f((unsigned short)hv[7]), accv[7]);
      }

    const int qy = y0 + qy_l, qx = x0 + qx_l;
    float vo[8];
    #pragma unroll
    for (int e = 0; e < 8; ++e) vo[e] = Osm[q * 36 + dq8 * 8 + e] + accv[e];
    ushort4 o0 = { f2bf(vo[0]), f2bf(vo[1]), f2bf(vo[2]), f2bf(vo[3]) };
    ushort4 o1 = { f2bf(vo[4]), f2bf(vo[5]), f2bf(vo[6]), f2bf(vo[7]) };
    unsigned short* op = &o_bf[((size_t)((n * HWDIM + qy) * HWDIM + qx)) * 256 + c0];
    *(ushort4*)op = o0;
    *(ushort4*)&op[4] = o1;
  }
}

// ---------------------------------------------------------------------------
extern "C" void kernel_launch(void* const* d_in, const int* in_sizes, int n_in,
                              void* d_out, int out_size, void* d_ws, size_t ws_size,
                              hipStream_t stream)
{
  const float* x      = (const float*)d_in[0];
  const float* W_qkv  = (const float*)d_in[1];
  const float* b_qkv  = (const float*)d_in[2];
  const float* lepe_w = (const float*)d_in[3];
  const float* lepe_b = (const float*)d_in[4];
  const float* W_o    = (const float*)d_in[5];
  const float* b_o    = (const float*)d_in[6];
  float* out = (float*)d_out;

  char* ws = (char*)d_ws;
  const size_t IMG = (size_t)NPIX * 256;          // elems per image buffer
  unsigned short* x_bf    = (unsigned short*)(ws);
  unsigned short* q_bf    = (unsigned short*)(ws + 2*IMG);
  unsigned short* k_bf    = (unsigned short*)(ws + 4*IMG);
  unsigned short* v_bf    = (unsigned short*)(ws + 6*IMG);
  unsigned short* attn_bf = (unsigned short*)(ws + 8*IMG);
  unsigned short* Wt_qkv  = (unsigned short*)(ws + 10*IMG);
  unsigned short* Wt_o    = (unsigned short*)(ws + 10*IMG + 393216);
  float*          b_s     = (float*)         (ws + 10*IMG + 393216 + 131072);
  float*          q_win   = (float*)         (ws + 10*IMG + 393216 + 131072 + 4096);
  float*          k_win   = q_win + (size_t)NBATCH * P2 * 256;
  int*            ridx    = (int*)(k_win + (size_t)NBATCH * P2 * 256);
  float*          Wc      = (float*)(ridx + (size_t)NBATCH * P2 * TOPK);

  fused_pre<<<NBATCH * P2 + 1052, 256, 0, stream>>>(
      x, W_qkv, b_qkv, W_o, lepe_w, x_bf, q_win, k_win, Wt_qkv, Wt_o, b_s, Wc);
  routing_topk<<<NBATCH * P2, 256, 0, stream>>>(q_win, k_win, ridx);
  gemm_mfma<0><<<dim3(196, 3), 512, 0, stream>>>(x_bf, Wt_qkv, b_s,
                                                 q_bf, k_bf, v_bf, nullptr);
  attn_mfma<<<NBATCH * P2 * HEADS, 256, 0, stream>>>(q_bf, k_bf, v_bf, ridx,
                                                     Wc, lepe_b, attn_bf);
  gemm_mfma<1><<<dim3(196, 1), 512, 0, stream>>>(attn_bf, Wt_o, b_o,
                                                 nullptr, nullptr, nullptr, out);
}